// Round 14
// baseline (192.132 us; speedup 1.0000x reference)
//
#include <hip/hip_runtime.h>

#define NN 20000
#define NE 640000
#define NET (NE + NN)   // 660000 edges incl. self-loops
#define NB 128          // dst buckets
#define RR 157          // nodes per bucket (ceil 20000/128)
#define NSL 256         // edge slices
#define ESL4 625        // int4 per slice (2500 edges)

typedef __attribute__((ext_vector_type(8))) short bf16x8;
typedef __attribute__((ext_vector_type(4))) float f32x4;
typedef __attribute__((ext_vector_type(2))) float f32x2;

__device__ inline ushort f2bf_rne(float x) {
    unsigned u = __float_as_uint(x);
    return (ushort)((u + 0x7FFFu + ((u >> 16) & 1u)) >> 16);
}
__device__ inline float bf2f(ushort u) {
    return __uint_as_float(((unsigned)u) << 16);
}
__device__ inline void split2(float x, ushort& hi, ushort& lo) {
    unsigned u = __float_as_uint(x);
    unsigned r = (u + 0x7FFFu + ((u >> 16) & 1u)) & 0xFFFF0000u;  // RNE to bf16
    hi = (ushort)(r >> 16);
    lo = f2bf_rne(x - __uint_as_float(r));   // x - hi is exact
}
__device__ inline float rlane(float x, int k) {
    return __int_as_float(__builtin_amdgcn_readlane(__float_as_int(x), k));
}

// Fragment layout for B[K][N]: vec-index (ctile*K32 + k32)*64 + ln holds bf16x8
// with element j = B[k32*32 + (ln>>4)*8 + j][ctile*16 + (ln&15)].

// ---- csrA: per-slice bucket histogram + folds + PARALLEL fragment packs ----
__global__ void csrA_kernel(const int* __restrict__ ei, int* __restrict__ cnt,
                            const float* __restrict__ W1, const float* __restrict__ as1,
                            const float* __restrict__ ad1, float* __restrict__ w1f,
                            const float* __restrict__ W2, const float* __restrict__ as2,
                            const float* __restrict__ ad2, float* __restrict__ w2f,
                            const float* __restrict__ W_ih,
                            const float* __restrict__ W_I, const float* __restrict__ b_I,
                            const float* __restrict__ W_R, const float* __restrict__ b_R,
                            const float* __restrict__ W_sir, const float* __restrict__ b_sir,
                            ushort* __restrict__ w1fh, ushort* __restrict__ w1fl,
                            ushort* __restrict__ w2fh, ushort* __restrict__ w2fl,
                            ushort* __restrict__ w3fh, ushort* __restrict__ w3fl,
                            ushort* __restrict__ wtfh, ushort* __restrict__ wtfl,
                            float* __restrict__ wc, float* __restrict__ wb) {
    int b = blockIdx.x, t = threadIdx.x;
    if (b < NSL) {
        __shared__ int h[NB];
        if (t < NB) h[t] = 0;
        __syncthreads();
        const int4* d4 = (const int4*)(ei + NE);
        for (int i = t; i < ESL4; i += 256) {
            int4 d = d4[b * ESL4 + i];
            atomicAdd(&h[(unsigned)d.x / RR], 1);
            atomicAdd(&h[(unsigned)d.y / RR], 1);
            atomicAdd(&h[(unsigned)d.z / RR], 1);
            atomicAdd(&h[(unsigned)d.w / RR], 1);
        }
        __syncthreads();
        if (t < NB) cnt[t * NSL + b] = h[t];   // bucket-major
    } else if (b == NSL) {
        if (t < 128) {
            int k = t;
#pragma unroll
            for (int hh = 0; hh < 4; hh++) {
                float s1 = 0.f, s2 = 0.f;
                for (int c = 0; c < 64; c++) {
                    float w = W1[k * 256 + hh * 64 + c];
                    s1 += w * as1[hh * 64 + c];
                    s2 += w * ad1[hh * 64 + c];
                }
                w1f[k * 8 + hh] = s1;
                w1f[k * 8 + 4 + hh] = s2;
            }
        }
    } else if (b == NSL + 1) {
        int k = t;
        float s1 = 0.f, s2 = 0.f;
        for (int c = 0; c < 128; c++) {
            float w = W2[k * 128 + c];
            s1 += w * as2[c];
            s2 += w * ad2[c];
        }
        w2f[k * 2] = s1;
        w2f[k * 2 + 1] = s2;
    } else if (b == NSL + 2) {
        if (t < 32) {
            int p = t;
            const float* Wr = (p < 15) ? W_I + p * 130
                            : (p < 30) ? W_R + (p - 15) * 130
                                       : W_sir + (p - 30) * 130;
            wc[p * 2] = Wr[128];
            wc[p * 2 + 1] = Wr[129];
            wb[p] = (p < 15) ? b_I[p] : (p < 30) ? b_R[p - 15] : b_sir[p - 30];
        }
    } else {
        int pb = b - (NSL + 3);   // 0..57
        if (pb < 16) {
            // W1 [K=128][N=256]: K32=4
            int base = pb * 2048;
#pragma unroll
            for (int q = 0; q < 8; q++) {
                int i = base + t + q * 256;
                int j = i & 7, ln = (i >> 3) & 63, rem = i >> 9;
                int k32 = rem & 3, n16 = rem >> 2;
                int k = k32 * 32 + ((ln >> 4) << 3) + j;
                int n = n16 * 16 + (ln & 15);
                ushort h, l; split2(W1[k * 256 + n], h, l);
                w1fh[i] = h; w1fl[i] = l;
            }
        } else if (pb < 32) {
            // W2 [K=256][N=128]: K32=8
            int base = (pb - 16) * 2048;
#pragma unroll
            for (int q = 0; q < 8; q++) {
                int i = base + t + q * 256;
                int j = i & 7, ln = (i >> 3) & 63, rem = i >> 9;
                int k32 = rem & 7, n16 = rem >> 3;
                int k = k32 * 32 + ((ln >> 4) << 3) + j;
                int n = n16 * 16 + (ln & 15);
                ushort h, l; split2(W2[k * 128 + n], h, l);
                w2fh[i] = h; w2fl[i] = l;
            }
        } else if (pb < 56) {
            // W_ih^T [K=128][N=384] (B[k][n] = W_ih[n*128+k]): K32=4
            int base = (pb - 32) * 2048;
#pragma unroll
            for (int q = 0; q < 8; q++) {
                int i = base + t + q * 256;
                int j = i & 7, ln = (i >> 3) & 63, rem = i >> 9;
                int k32 = rem & 3, n16 = rem >> 2;
                int k = k32 * 32 + ((ln >> 4) << 3) + j;
                int n = n16 * 16 + (ln & 15);
                ushort h, l; split2(W_ih[n * 128 + k], h, l);
                w3fh[i] = h; w3fl[i] = l;
            }
        } else {
            // heads Wt (N=32, K=128): K32=4
            int base = (pb - 56) * 2048;
#pragma unroll
            for (int q = 0; q < 8; q++) {
                int i = base + t + q * 256;
                int j = i & 7, ln = (i >> 3) & 63, rem = i >> 9;
                int k32 = rem & 3, n16 = rem >> 2;
                int k = k32 * 32 + ((ln >> 4) << 3) + j;
                int n = n16 * 16 + (ln & 15);
                const float* Wr = (n < 15) ? W_I + n * 130
                                : (n < 30) ? W_R + (n - 15) * 130
                                           : W_sir + (n - 30) * 130;
                ushort h, l; split2(Wr[k], h, l);
                wtfh[i] = h; wtfl[i] = l;
            }
        }
    }
}

// ---- csrB: exclusive scan of 32768 counts, 32/thread ----
__global__ void csrB_kernel(const int* __restrict__ cnt, int* __restrict__ sbase) {
    __shared__ int ws1[16], ws2[16];
    int t = threadIdx.x, wv = t >> 6, ln = t & 63;
    int base = t * 32;
    int loc[32];
    int run = 0;
#pragma unroll
    for (int q = 0; q < 32; q++) { loc[q] = run; run += cnt[base + q]; }
    int s = run;
#pragma unroll
    for (int o = 1; o < 64; o <<= 1) { int u = __shfl_up(s, o, 64); if (ln >= o) s += u; }
    if (ln == 63) ws1[wv] = s;
    __syncthreads();
    if (t < 16) {
        int sv = ws1[t];
#pragma unroll
        for (int o = 1; o < 16; o <<= 1) { int u = __shfl_up(sv, o, 16); if (t >= o) sv += u; }
        ws2[t] = sv;
    }
    __syncthreads();
    int excl = (wv ? ws2[wv - 1] : 0) + s - run;
#pragma unroll
    for (int q = 0; q < 32; q++) sbase[base + q] = excl + loc[q];
}

// ---- csrC: slice scatter into packed ebuf (src | dst<<15) + alar_cast ----
__global__ void csrC_kernel(const int* __restrict__ ei, const int* __restrict__ sbase,
                            int* __restrict__ ebuf, const float* __restrict__ X,
                            const float* __restrict__ wf, ushort* __restrict__ Xbf,
                            float* __restrict__ al, float* __restrict__ ar) {
    int b = blockIdx.x, t = threadIdx.x;
    if (b < NSL) {
        __shared__ int cur[NB];
        if (t < NB) cur[t] = sbase[t * NSL + b];
        __syncthreads();
        const int4* s4 = (const int4*)ei;
        const int4* d4 = (const int4*)(ei + NE);
        for (int i = t; i < ESL4; i += 256) {
            int4 sv = s4[b * ESL4 + i];
            int4 dv = d4[b * ESL4 + i];
            int p;
            p = atomicAdd(&cur[(unsigned)dv.x / RR], 1); ebuf[p] = sv.x | (dv.x << 15);
            p = atomicAdd(&cur[(unsigned)dv.y / RR], 1); ebuf[p] = sv.y | (dv.y << 15);
            p = atomicAdd(&cur[(unsigned)dv.z / RR], 1); ebuf[p] = sv.z | (dv.z << 15);
            p = atomicAdd(&cur[(unsigned)dv.w / RR], 1); ebuf[p] = sv.w | (dv.w << 15);
        }
    } else {
        __shared__ float ws[8][128];
        for (int i = t; i < 1024; i += 256) ws[i & 7][i >> 3] = wf[i];
        __syncthreads();
        int wv = t >> 6, ln = t & 63;
        int n = (b - NSL) * 4 + wv;
        float2 xv = *(const float2*)(X + (size_t)n * 128 + ln * 2);
        ushort2 ub;
        ub.x = f2bf_rne(xv.x);
        ub.y = f2bf_rne(xv.y);
        *(ushort2*)(Xbf + (size_t)n * 128 + ln * 2) = ub;
        float p[8];
#pragma unroll
        for (int o = 0; o < 8; o++) p[o] = xv.x * ws[o][ln * 2] + xv.y * ws[o][ln * 2 + 1];
#pragma unroll
        for (int off = 32; off > 0; off >>= 1)
#pragma unroll
            for (int o = 0; o < 8; o++) p[o] += __shfl_xor(p[o], off, 64);
        if (ln == 0) {
#pragma unroll
            for (int h = 0; h < 4; h++) {
                al[n * 4 + h] = p[h];
                ar[n * 4 + h] = p[4 + h];
            }
        }
    }
}

// ---- csrD: per-bucket local CSR build (packed ebuf) ----
__global__ void csrD_kernel(const int* __restrict__ ebuf, const int* __restrict__ sbase,
                            int* __restrict__ offs, int* __restrict__ csr_src) {
    __shared__ int hist[RR], lcur[RR];
    int b = blockIdx.x, t = threadIdx.x;
    int lo = b * RR;
    int Ra = min(RR, NN - lo);
    int e0 = sbase[b * NSL];
    int e1 = (b < NB - 1) ? sbase[(b + 1) * NSL] : NE;
    int m = e1 - e0;
    for (int i = t; i < Ra; i += 256) hist[i] = 0;
    __syncthreads();
    for (int j = t; j < m; j += 256) atomicAdd(&hist[(ebuf[e0 + j] >> 15) - lo], 1);
    __syncthreads();
    if (t < 64) {
        int cbase = e0 + lo;
        int carry = 0;
#pragma unroll
        for (int c = 0; c < 3; c++) {
            int i = c * 64 + t;
            int v = (i < Ra) ? hist[i] + 1 : 0;   // +1 self-loop
            int s = v;
#pragma unroll
            for (int o = 1; o < 64; o <<= 1) { int u = __shfl_up(s, o, 64); if (t >= o) s += u; }
            if (i < Ra) {
                int off = cbase + carry + s - v;
                offs[lo + i] = off;
                lcur[i] = off;
            }
            carry += __shfl(s, 63, 64);
        }
    }
    if (b == 0 && t == 255) offs[NN] = NET;
    __syncthreads();
    for (int i = t; i < Ra; i += 256) csr_src[lcur[i] + hist[i]] = lo + i;  // self-loop last
    __syncthreads();
    for (int j = t; j < m; j += 256) {
        int p = ebuf[e0 + j];
        int pos = atomicAdd(&lcur[(p >> 15) - lo], 1);
        csr_src[pos] = p & 0x7FFF;
    }
}

// ---- GAT gather: wave/node, no-max softmax, 16 loads in flight ----
template <int H, bool FUSE>
__launch_bounds__(256)
__global__ void gat_gather_w(const ushort* __restrict__ X, const float* __restrict__ al,
                             const float* __restrict__ ar, const int* __restrict__ offs,
                             const int* __restrict__ csr, const float* __restrict__ bias,
                             void* __restrict__ outp) {
    int t = threadIdx.x;
    int wv = t >> 6, ln = t & 63;
    int n = blockIdx.x * 4 + wv;
    int e0 = offs[n], e1 = offs[n + 1];

    float arv[H], srun[H];
    f32x2 acc2[H];
#pragma unroll
    for (int h = 0; h < H; h++) {
        arv[h] = ar[n * H + h];
        srun[h] = 0.f;
        acc2[h][0] = 0.f; acc2[h][1] = 0.f;
    }
    const ushort* Xc = X + ln * 2;

    for (int base = e0; base < e1; base += 64) {
        int cnt = e1 - base; if (cnt > 64) cnt = 64;
        bool vld = ln < cnt;
        int src = vld ? csr[base + ln] : 0;
        float wgt[H];
        {
            float av[H];
            if (H == 4) {
                float4 a4 = *(const float4*)(al + (size_t)src * 4);
                av[0] = a4.x; av[H > 1 ? 1 : 0] = a4.y;
                av[H > 2 ? 2 : 0] = a4.z; av[H > 3 ? 3 : 0] = a4.w;
            } else {
                av[0] = al[src];
            }
#pragma unroll
            for (int h = 0; h < H; h++) {
                float lg = av[h] + arv[h];
                lg = lg > 0.f ? lg : 0.2f * lg;
                wgt[h] = vld ? __expf(lg) : 0.f;
            }
        }
        float ls[H];
#pragma unroll
        for (int h = 0; h < H; h++) ls[h] = wgt[h];
#pragma unroll
        for (int off = 32; off > 0; off >>= 1)
#pragma unroll
            for (int h = 0; h < H; h++) ls[h] += __shfl_xor(ls[h], off, 64);
#pragma unroll
        for (int h = 0; h < H; h++) srun[h] += ls[h];

        int k = 0;
        for (; k + 16 <= cnt; k += 16) {
            int s[16];
            unsigned u[16];
#pragma unroll
            for (int q = 0; q < 16; q++) s[q] = __builtin_amdgcn_readlane(src, k + q);
#pragma unroll
            for (int q = 0; q < 16; q++) u[q] = *(const unsigned*)(Xc + (size_t)s[q] * 128);
#pragma unroll
            for (int q = 0; q < 16; q++) {
                f32x2 xv;
                xv[0] = __uint_as_float(u[q] << 16);
                xv[1] = __uint_as_float(u[q] & 0xffff0000u);
#pragma unroll
                for (int h = 0; h < H; h++) {
                    float w = rlane(wgt[h], k + q);
                    f32x2 ww; ww[0] = w; ww[1] = w;
                    acc2[h] = __builtin_elementwise_fma(ww, xv, acc2[h]);
                }
            }
        }
        for (; k + 8 <= cnt; k += 8) {
            int s[8];
            unsigned u[8];
#pragma unroll
            for (int q = 0; q < 8; q++) s[q] = __builtin_amdgcn_readlane(src, k + q);
#pragma unroll
            for (int q = 0; q < 8; q++) u[q] = *(const unsigned*)(Xc + (size_t)s[q] * 128);
#pragma unroll
            for (int q = 0; q < 8; q++) {
                f32x2 xv;
                xv[0] = __uint_as_float(u[q] << 16);
                xv[1] = __uint_as_float(u[q] & 0xffff0000u);
#pragma unroll
                for (int h = 0; h < H; h++) {
                    float w = rlane(wgt[h], k + q);
                    f32x2 ww; ww[0] = w; ww[1] = w;
                    acc2[h] = __builtin_elementwise_fma(ww, xv, acc2[h]);
                }
            }
        }
        for (; k < cnt; k++) {
            int s0 = __builtin_amdgcn_readlane(src, k);
            unsigned u0 = *(const unsigned*)(Xc + (size_t)s0 * 128);
            f32x2 xv;
            xv[0] = __uint_as_float(u0 << 16);
            xv[1] = __uint_as_float(u0 & 0xffff0000u);
#pragma unroll
            for (int h = 0; h < H; h++) {
                float w = rlane(wgt[h], k);
                f32x2 ww; ww[0] = w; ww[1] = w;
                acc2[h] = __builtin_elementwise_fma(ww, xv, acc2[h]);
            }
        }
    }
    if (FUSE) {
        ushort* out = (ushort*)outp;
        float inv = 1.f / srun[0];
        float v0 = acc2[0][0] * inv + bias[ln * 2];
        float v1 = acc2[0][1] * inv + bias[ln * 2 + 1];
        v0 = v0 > 0.f ? v0 : __expf(v0) - 1.f;
        v1 = v1 > 0.f ? v1 : __expf(v1) - 1.f;
        ushort2 o;
        o.x = f2bf_rne(v0);
        o.y = f2bf_rne(v1);
        *(ushort2*)(out + (size_t)n * 128 + ln * 2) = o;
    } else {
        ushort* out = (ushort*)outp;
#pragma unroll
        for (int h = 0; h < H; h++) {
            float inv = 1.f / srun[h];
            ushort2 o;
            o.x = f2bf_rne(acc2[h][0] * inv);
            o.y = f2bf_rne(acc2[h][1] * inv);
            *(ushort2*)(out + (size_t)n * (H * 128) + h * 128 + ln * 2) = o;
        }
    }
}

// ---- MFMA GEMM: A bf16 via LDS, B pre-packed fragment-order (no B LDS) ----
template <int ACT, bool OUTBF, int BN, bool ALAR>
__launch_bounds__(256)
__global__ void gemm_fr(const ushort* __restrict__ A, const ushort* __restrict__ Bfh,
                        const ushort* __restrict__ Bfl, const float* __restrict__ bias,
                        void* __restrict__ Cptr, int M, int K, int lda, int ldc,
                        int zA, int zB, int zC, const float* __restrict__ w2f,
                        float* __restrict__ al2, float* __restrict__ ar2) {
    constexpr int NF = BN / 32;
    __shared__ ushort Ah[128 * 64];
    __shared__ float s_w2f[ALAR ? 256 : 1][2];
    int tid = threadIdx.x;
    int z = blockIdx.z;
    int bm = blockIdx.x * 128;
    int ny = blockIdx.y * BN;
    int wid = tid >> 6, ln = tid & 63;
    int wm = wid >> 1, wn = wid & 1;
    int K32v = K >> 5;
    const bf16x8* BfhV = (const bf16x8*)Bfh;
    const bf16x8* BflV = (const bf16x8*)Bfl;
    f32x4 acc[4][NF];
#pragma unroll
    for (int a = 0; a < 4; a++)
#pragma unroll
        for (int b = 0; b < NF; b++)
#pragma unroll
            for (int j = 0; j < 4; j++) acc[a][b][j] = 0.f;
    float p0a[8], p1a[8];
    if (ALAR) {
#pragma unroll
        for (int i = 0; i < 8; i++) { p0a[i] = 0.f; p1a[i] = 0.f; }
        s_w2f[tid][0] = w2f[tid * 2];
        s_w2f[tid][1] = w2f[tid * 2 + 1];
        __syncthreads();
    }
    size_t abase = (size_t)z * zA;
    int bcb = z * zB + ny;
    int ct[NF];
#pragma unroll
    for (int nf = 0; nf < NF; nf++) ct[nf] = (bcb + wn * (BN / 2) + nf * 16) >> 4;

    for (int k0 = 0; k0 < K; k0 += 64) {
#pragma unroll
        for (int i = 0; i < 8; i++) {
            int idx = tid + i * 256;
            int r = idx >> 4, c4 = (idx & 15) * 4;
            int gr = bm + r;
            ushort4 v = make_ushort4(0, 0, 0, 0);
            if (gr < M) v = *(const ushort4*)(A + abase + (size_t)gr * lda + k0 + c4);
            int ab = (r * 128 + c4 * 2) ^ ((r & 7) << 4);
            *(ushort4*)((char*)Ah + ab) = v;
            if (ALAR) {
                int kk = k0 + c4;
                float x0 = bf2f(v.x), x1 = bf2f(v.y), x2 = bf2f(v.z), x3 = bf2f(v.w);
                p0a[i] = fmaf(x0, s_w2f[kk][0], p0a[i]);
                p0a[i] = fmaf(x1, s_w2f[kk + 1][0], p0a[i]);
                p0a[i] = fmaf(x2, s_w2f[kk + 2][0], p0a[i]);
                p0a[i] = fmaf(x3, s_w2f[kk + 3][0], p0a[i]);
                p1a[i] = fmaf(x0, s_w2f[kk][1], p1a[i]);
                p1a[i] = fmaf(x1, s_w2f[kk + 1][1], p1a[i]);
                p1a[i] = fmaf(x2, s_w2f[kk + 2][1], p1a[i]);
                p1a[i] = fmaf(x3, s_w2f[kk + 3][1], p1a[i]);
            }
        }
        __syncthreads();
#pragma unroll
        for (int ks = 0; ks < 2; ks++) {
            int k32 = (k0 >> 5) + ks;
            int kb = ks * 64 + (ln >> 4) * 16;
            bf16x8 ah[4];
#pragma unroll
            for (int mf = 0; mf < 4; mf++) {
                int r = wm * 64 + mf * 16 + (ln & 15);
                int ab = (r * 128 + kb) ^ ((r & 7) << 4);
                ah[mf] = *(bf16x8*)((char*)Ah + ab);
            }
#pragma unroll
            for (int nf = 0; nf < NF; nf++) {
                size_t fb = (size_t)(ct[nf] * K32v + k32) * 64 + ln;
                bf16x8 bh = BfhV[fb];
                bf16x8 bl = BflV[fb];
#pragma unroll
                for (int mf = 0; mf < 4; mf++) {
                    acc[mf][nf] = __builtin_amdgcn_mfma_f32_16x16x32_bf16(ah[mf], bh, acc[mf][nf], 0, 0, 0);
                    acc[mf][nf] = __builtin_amdgcn_mfma_f32_16x16x32_bf16(ah[mf], bl, acc[mf][nf], 0, 0, 0);
                }
            }
        }
        __syncthreads();
    }
    if (ALAR) {
#pragma unroll
        for (int i = 0; i < 8; i++) {
            float p0 = p0a[i], p1 = p1a[i];
#pragma unroll
            for (int off = 8; off > 0; off >>= 1) {
                p0 += __shfl_xor(p0, off, 16);
                p1 += __shfl_xor(p1, off, 16);
            }
            if ((tid & 15) == 0) {
                int gr = bm + (tid >> 4) + i * 16;
                if (gr < M) { al2[gr] = p0; ar2[gr] = p1; }
            }
        }
    }
    float* Cf = (float*)Cptr;
    ushort* Cu = (ushort*)Cptr;
#pragma unroll
    for (int mf = 0; mf < 4; mf++)
#pragma unroll
        for (int nf = 0; nf < NF; nf++) {
            int colL = ny + wn * (BN / 2) + nf * 16 + (ln & 15);
#pragma unroll
            for (int j = 0; j < 4; j++) {
                int row = bm + wm * 64 + mf * 16 + (ln >> 4) * 4 + j;
                if (row < M) {
                    float v = acc[mf][nf][j];
                    if (ACT) {
                        v += bias[z * zC + colL];
                        v = v > 0.f ? v : (__expf(v) - 1.f);
                    }
                    size_t ci = (size_t)row * ldc + z * zC + colL;
                    if (OUTBF) Cu[ci] = f2bf_rne(v);
                    else       Cf[ci] = v;
                }
            }
        }
}

// ---- tail: GRU elementwise (reads gi bf16) + heads MFMA (frag-B) + SIR ----
__launch_bounds__(256)
__global__ void tail_kernel(const ushort* __restrict__ gi, const float* __restrict__ b_ih,
                            const float* __restrict__ b_hh, const ushort* __restrict__ wtfh,
                            const ushort* __restrict__ wtfl, const float* __restrict__ wc,
                            const float* __restrict__ wb, const float* __restrict__ cI,
                            const float* __restrict__ cR, const float* __restrict__ Npop,
                            const float* __restrict__ I0, const float* __restrict__ R0,
                            float* __restrict__ out_h, float* __restrict__ predI,
                            float* __restrict__ predR, float* __restrict__ phyI,
                            float* __restrict__ phyR) {
    __shared__ ushort As[64 * 128];   // 16 KB: swizzled h_bf tile
    __shared__ float s_ab[2][64];
    __shared__ float s_ci[64], s_cr[64];
    int t = threadIdx.x;
    int bm = blockIdx.x * 64;
    int wid = t >> 6, ln = t & 63;
    const bf16x8* WTh = (const bf16x8*)wtfh;
    const bf16x8* WTl = (const bf16x8*)wtfl;
    if (t < 64) {
        int n = bm + t;
        s_ci[t] = (n < NN) ? cI[n] : 0.f;
        s_cr[t] = (n < NN) ? cR[n] : 0.f;
    }
    // GRU elementwise: 2048 (row, c4) pieces
    for (int i = t; i < 2048; i += 256) {
        int r = i >> 5, c4 = (i & 31) * 4;
        int n = bm + r;
        ushort4 ua = make_ushort4(0, 0, 0, 0), ub = ua, uc = ua;
        if (n < NN) {
            const ushort* g = gi + (size_t)n * 384;
            ua = *(const ushort4*)(g + c4);
            ub = *(const ushort4*)(g + 128 + c4);
            uc = *(const ushort4*)(g + 256 + c4);
        }
        float gaa[4] = {bf2f(ua.x), bf2f(ua.y), bf2f(ua.z), bf2f(ua.w)};
        float gba[4] = {bf2f(ub.x), bf2f(ub.y), bf2f(ub.z), bf2f(ub.w)};
        float gca[4] = {bf2f(uc.x), bf2f(uc.y), bf2f(uc.z), bf2f(uc.w)};
        float hv[4];
#pragma unroll
        for (int q = 0; q < 4; q++) {
            int c = c4 + q;
            float rr = 1.f / (1.f + __expf(-(gaa[q] + b_ih[c] + b_hh[c])));
            float zz = 1.f / (1.f + __expf(-(gba[q] + b_ih[128 + c] + b_hh[128 + c])));
            float xx = gca[q] + b_ih[256 + c] + rr * b_hh[256 + c];
            xx = fminf(fmaxf(xx, -15.f), 15.f);
            float e2 = __expf(2.f * xx);
            hv[q] = (1.f - zz) * (e2 - 1.f) / (e2 + 1.f);
        }
        if (n < NN)
            *(float4*)(out_h + (size_t)n * 128 + c4) = make_float4(hv[0], hv[1], hv[2], hv[3]);
        ushort4 hb = make_ushort4(f2bf_rne(hv[0]), f2bf_rne(hv[1]), f2bf_rne(hv[2]), f2bf_rne(hv[3]));
        int ab = (r * 256 + c4 * 2) ^ ((r & 7) << 4);
        *(ushort4*)((char*)As + ab) = hb;
    }
    __syncthreads();
    // heads MFMA: wave wid -> rows wid*16..+15, 32 cols, B frags direct from global
    f32x4 acc2[2];
#pragma unroll
    for (int nf = 0; nf < 2; nf++)
#pragma unroll
        for (int j = 0; j < 4; j++) acc2[nf][j] = 0.f;
#pragma unroll
    for (int ks = 0; ks < 4; ks++) {
        int r = wid * 16 + (ln & 15);
        int abyte = (r * 256 + ks * 64 + (ln >> 4) * 16) ^ ((r & 7) << 4);
        bf16x8 ah = *(bf16x8*)((char*)As + abyte);
#pragma unroll
        for (int nf = 0; nf < 2; nf++) {
            size_t fb = (size_t)(nf * 4 + ks) * 64 + ln;
            bf16x8 bh = WTh[fb];
            bf16x8 bl = WTl[fb];
            acc2[nf] = __builtin_amdgcn_mfma_f32_16x16x32_bf16(ah, bh, acc2[nf], 0, 0, 0);
            acc2[nf] = __builtin_amdgcn_mfma_f32_16x16x32_bf16(ah, bl, acc2[nf], 0, 0, 0);
        }
    }
    // epilogue: bias + cI/cR cols, write preds, stash alpha/beta logits
#pragma unroll
    for (int nf = 0; nf < 2; nf++) {
        int col = nf * 16 + (ln & 15);
#pragma unroll
        for (int j = 0; j < 4; j++) {
            int rl = wid * 16 + (ln >> 4) * 4 + j;
            int n = bm + rl;
            float v = acc2[nf][j] + s_ci[rl] * wc[col * 2] + s_cr[rl] * wc[col * 2 + 1] + wb[col];
            if (n < NN) {
                if (col < 15)      predI[(size_t)n * 15 + col] = v;
                else if (col < 30) predR[(size_t)n * 15 + col - 15] = v;
            }
            if (col == 30) s_ab[0][rl] = v;
            if (col == 31) s_ab[1][rl] = v;
        }
    }
    __syncthreads();
    if (t < 64) {
        int n = bm + t;
        if (n < NN) {
            float alpha = 1.f / (1.f + __expf(-s_ab[0][t]));
            float beta  = 1.f / (1.f + __expf(-s_ab[1][t]));
            float Nv = Npop[n];
            float Iv = I0[n], Rv = R0[n];
            float SoN = (Nv - Iv - Rv) / Nv;
            for (int st = 0; st < 15; st++) {
                float dI = alpha * Iv * SoN - beta * Iv;
                float dR = beta * Iv;
                phyI[(size_t)n * 15 + st] = dI;
                phyR[(size_t)n * 15 + st] = dR;
                Iv += dI; Rv += dR;
            }
        }
    }
}

extern "C" void kernel_launch(void* const* d_in, const int* in_sizes, int n_in,
                              void* d_out, int out_size, void* d_ws, size_t ws_size,
                              hipStream_t stream) {
    const float* dynamic = (const float*)d_in[0];
    const int*   ei      = (const int*)d_in[1];
    const float* cI      = (const float*)d_in[2];
    const float* cR      = (const float*)d_in[3];
    const float* Npop    = (const float*)d_in[4];
    const float* I0      = (const float*)d_in[5];
    const float* R0      = (const float*)d_in[6];
    const float* W1      = (const float*)d_in[9];
    const float* a_src1  = (const float*)d_in[10];
    const float* a_dst1  = (const float*)d_in[11];
    const float* b1      = (const float*)d_in[12];
    const float* W2      = (const float*)d_in[13];
    const float* a_src2  = (const float*)d_in[14];
    const float* a_dst2  = (const float*)d_in[15];
    const float* b2      = (const float*)d_in[16];
    const float* W_ih    = (const float*)d_in[17];
    const float* b_ih    = (const float*)d_in[19];
    const float* b_hh    = (const float*)d_in[20];
    const float* W_I     = (const float*)d_in[21];
    const float* b_I     = (const float*)d_in[22];
    const float* W_R     = (const float*)d_in[23];
    const float* b_R     = (const float*)d_in[24];
    const float* W_sir   = (const float*)d_in[25];
    const float* b_sir   = (const float*)d_in[26];
    float* out = (float*)d_out;
    float* out_predI = out;
    float* out_predR = out + 300000;
    float* out_phyI  = out + 600000;
    float* out_phyR  = out + 900000;
    float* out_h     = out + 1200000;   // [20000][128] f32

    // ---- workspace layout ----
    int* wsi = (int*)d_ws;
    int* offs    = wsi;              // 20001 (pad 20096)
    int* csr_src = wsi + 20096;      // 660000 (pad 660096)
    int* cnt     = wsi + 680192;     // 32768
    int* sbase   = wsi + 712960;     // 32768
    float* fp = (float*)(wsi + 745728);
    float* w1f = fp; fp += 1152;     // 128*8
    float* w2f = fp; fp += 512;      // 256*2
    float* wc  = fp; fp += 64;
    float* wb  = fp; fp += 64;
    float* al1 = fp; fp += 80128;    // 20000*4
    float* ar1 = fp; fp += 80128;
    float* al2 = fp; fp += 20096;
    float* ar2 = fp; fp += 20096;
    // fragment-packed bf16 weights (ushort)
    ushort* wub  = (ushort*)fp; fp += 118784;  // 237568 ushorts
    ushort* w1fh = wub;            // 32768
    ushort* w1fl = wub + 32768;
    ushort* w2fh = wub + 65536;    // 32768
    ushort* w2fl = wub + 98304;
    ushort* w3fh = wub + 131072;   // 49152
    ushort* w3fl = wub + 180224;
    ushort* wtfh = wub + 229376;   // 4096
    ushort* wtfl = wub + 233472;
    ushort* dyn_bf = (ushort*)fp; fp += 1280000;   // 20000*128 bf16
    ushort* x1u = (ushort*)fp; fp += 2560000;      // [20000][256] bf16
    ushort* x2u = x1u;                             // [20000][128] bf16 (x1 dead)
    float* R  = fp; fp += 7680000;                 // ebuf / agg_bf / xl2_bf / gi_bf
    int* ebuf = (int*)R;                           // [640000] packed src|dst<<15
    ushort* agg_bf = (ushort*)R;                   // [20000][512] bf16
    ushort* xl2_bf = (ushort*)R;                   // [20000][128] bf16 (after agg dead)
    ushort* gi_bf  = (ushort*)R;                   // [20000][384] bf16 (after xl2 dead)

    // CSR build + weight prep (packs parallelized over 58 blocks)
    csrA_kernel<<<NSL + 3 + 58, 256, 0, stream>>>(ei, cnt, W1, a_src1, a_dst1, w1f,
                                                  W2, a_src2, a_dst2, w2f, W_ih,
                                                  W_I, b_I, W_R, b_R, W_sir, b_sir,
                                                  w1fh, w1fl, w2fh, w2fl, w3fh, w3fl,
                                                  wtfh, wtfl, wc, wb);
    csrB_kernel<<<1, 1024, 0, stream>>>(cnt, sbase);
    csrC_kernel<<<NSL + 5000, 256, 0, stream>>>(ei, sbase, ebuf, dynamic, w1f,
                                                dyn_bf, al1, ar1);
    csrD_kernel<<<NB, 256, 0, stream>>>(ebuf, sbase, offs, csr_src);

    // GAT layer 1
    gat_gather_w<4, false><<<5000, 256, 0, stream>>>(dyn_bf, al1, ar1, offs, csr_src, nullptr, agg_bf);
    gemm_fr<1, true, 64, false><<<dim3(157, 1, 4), 256, 0, stream>>>(
        agg_bf, w1fh, w1fl, b1, x1u, NN, 128, 512, 256, 128, 64, 64,
        nullptr, nullptr, nullptr);

    // GAT layer 2 (al2/ar2 fused into GEMM via w2f fold)
    gemm_fr<0, true, 128, true><<<dim3(157, 1, 1), 256, 0, stream>>>(
        x1u, w2fh, w2fl, nullptr, xl2_bf, NN, 256, 256, 128, 0, 0, 0,
        w2f, al2, ar2);
    gat_gather_w<1, true><<<5000, 256, 0, stream>>>(xl2_bf, al2, ar2, offs, csr_src, b2, x2u);

    // gi = x2 @ W_ih^T (N=384 via blockIdx.y), bf16 output
    gemm_fr<0, true, 128, false><<<dim3(157, 3, 1), 256, 0, stream>>>(
        x2u, w3fh, w3fl, nullptr, gi_bf, NN, 128, 128, 384, 0, 0, 0,
        nullptr, nullptr, nullptr);

    // GRU + heads + SIR
    tail_kernel<<<313, 256, 0, stream>>>(gi_bf, b_ih, b_hh, wtfh, wtfl, wc, wb,
                                         cI, cR, Npop, I0, R0, out_h,
                                         out_predI, out_predR, out_phyI, out_phyR);
}

// Round 15
// 173.614 us; speedup vs baseline: 1.1067x; 1.1067x over previous
//
#include <hip/hip_runtime.h>

#define NN 20000
#define NE 640000
#define NET (NE + NN)   // 660000 edges incl. self-loops
#define NB 256          // dst buckets
#define RR 79           // nodes per bucket (ceil 20000/256)
#define NSL 256         // edge slices
#define ESL4 625        // int4 per slice (2500 edges)

typedef __attribute__((ext_vector_type(8))) short bf16x8;
typedef __attribute__((ext_vector_type(4))) float f32x4;
typedef __attribute__((ext_vector_type(2))) float f32x2;

__device__ inline ushort f2bf_rne(float x) {
    unsigned u = __float_as_uint(x);
    return (ushort)((u + 0x7FFFu + ((u >> 16) & 1u)) >> 16);
}
__device__ inline float bf2f(ushort u) {
    return __uint_as_float(((unsigned)u) << 16);
}
__device__ inline void split2(float x, ushort& hi, ushort& lo) {
    unsigned u = __float_as_uint(x);
    unsigned r = (u + 0x7FFFu + ((u >> 16) & 1u)) & 0xFFFF0000u;  // RNE to bf16
    hi = (ushort)(r >> 16);
    lo = f2bf_rne(x - __uint_as_float(r));   // x - hi is exact
}
__device__ inline float rlane(float x, int k) {
    return __int_as_float(__builtin_amdgcn_readlane(__float_as_int(x), k));
}

// Fragment layout for B[K][N]: vec-index (ctile*K32 + k32)*64 + ln holds bf16x8
// with element j = B[k32*32 + (ln>>4)*8 + j][ctile*16 + (ln&15)].

// ---- csrA: per-slice bucket histogram + folds + PARALLEL fragment packs ----
__global__ void csrA_kernel(const int* __restrict__ ei, int* __restrict__ cnt,
                            const float* __restrict__ W1, const float* __restrict__ as1,
                            const float* __restrict__ ad1, float* __restrict__ w1f,
                            const float* __restrict__ W2, const float* __restrict__ as2,
                            const float* __restrict__ ad2, float* __restrict__ w2f,
                            const float* __restrict__ W_ih,
                            const float* __restrict__ W_I, const float* __restrict__ b_I,
                            const float* __restrict__ W_R, const float* __restrict__ b_R,
                            const float* __restrict__ W_sir, const float* __restrict__ b_sir,
                            ushort* __restrict__ w1fh, ushort* __restrict__ w1fl,
                            ushort* __restrict__ w2fh, ushort* __restrict__ w2fl,
                            ushort* __restrict__ w3fh, ushort* __restrict__ w3fl,
                            ushort* __restrict__ wtfh, ushort* __restrict__ wtfl,
                            float* __restrict__ wc, float* __restrict__ wb) {
    int b = blockIdx.x, t = threadIdx.x;
    if (b < NSL) {
        __shared__ int h[NB];
        h[t] = 0;
        __syncthreads();
        const int4* d4 = (const int4*)(ei + NE);
        for (int i = t; i < ESL4; i += 256) {
            int4 d = d4[b * ESL4 + i];
            atomicAdd(&h[(unsigned)d.x / RR], 1);
            atomicAdd(&h[(unsigned)d.y / RR], 1);
            atomicAdd(&h[(unsigned)d.z / RR], 1);
            atomicAdd(&h[(unsigned)d.w / RR], 1);
        }
        __syncthreads();
        cnt[t * NSL + b] = h[t];   // bucket-major
    } else if (b == NSL) {
        if (t < 128) {
            int k = t;
#pragma unroll
            for (int hh = 0; hh < 4; hh++) {
                float s1 = 0.f, s2 = 0.f;
                for (int c = 0; c < 64; c++) {
                    float w = W1[k * 256 + hh * 64 + c];
                    s1 += w * as1[hh * 64 + c];
                    s2 += w * ad1[hh * 64 + c];
                }
                w1f[k * 8 + hh] = s1;
                w1f[k * 8 + 4 + hh] = s2;
            }
        }
    } else if (b == NSL + 1) {
        int k = t;
        float s1 = 0.f, s2 = 0.f;
        for (int c = 0; c < 128; c++) {
            float w = W2[k * 128 + c];
            s1 += w * as2[c];
            s2 += w * ad2[c];
        }
        w2f[k * 2] = s1;
        w2f[k * 2 + 1] = s2;
    } else if (b == NSL + 2) {
        if (t < 32) {
            int p = t;
            const float* Wr = (p < 15) ? W_I + p * 130
                            : (p < 30) ? W_R + (p - 15) * 130
                                       : W_sir + (p - 30) * 130;
            wc[p * 2] = Wr[128];
            wc[p * 2 + 1] = Wr[129];
            wb[p] = (p < 15) ? b_I[p] : (p < 30) ? b_R[p - 15] : b_sir[p - 30];
        }
    } else {
        int pb = b - (NSL + 3);   // 0..57
        if (pb < 16) {
            // W1 [K=128][N=256]: K32=4
            int base = pb * 2048;
#pragma unroll
            for (int q = 0; q < 8; q++) {
                int i = base + t + q * 256;
                int j = i & 7, ln = (i >> 3) & 63, rem = i >> 9;
                int k32 = rem & 3, n16 = rem >> 2;
                int k = k32 * 32 + ((ln >> 4) << 3) + j;
                int n = n16 * 16 + (ln & 15);
                ushort h, l; split2(W1[k * 256 + n], h, l);
                w1fh[i] = h; w1fl[i] = l;
            }
        } else if (pb < 32) {
            // W2 [K=256][N=128]: K32=8
            int base = (pb - 16) * 2048;
#pragma unroll
            for (int q = 0; q < 8; q++) {
                int i = base + t + q * 256;
                int j = i & 7, ln = (i >> 3) & 63, rem = i >> 9;
                int k32 = rem & 7, n16 = rem >> 3;
                int k = k32 * 32 + ((ln >> 4) << 3) + j;
                int n = n16 * 16 + (ln & 15);
                ushort h, l; split2(W2[k * 128 + n], h, l);
                w2fh[i] = h; w2fl[i] = l;
            }
        } else if (pb < 56) {
            // W_ih^T [K=128][N=384] (B[k][n] = W_ih[n*128+k]): K32=4
            int base = (pb - 32) * 2048;
#pragma unroll
            for (int q = 0; q < 8; q++) {
                int i = base + t + q * 256;
                int j = i & 7, ln = (i >> 3) & 63, rem = i >> 9;
                int k32 = rem & 3, n16 = rem >> 2;
                int k = k32 * 32 + ((ln >> 4) << 3) + j;
                int n = n16 * 16 + (ln & 15);
                ushort h, l; split2(W_ih[n * 128 + k], h, l);
                w3fh[i] = h; w3fl[i] = l;
            }
        } else {
            // heads Wt (N=32, K=128): K32=4
            int base = (pb - 56) * 2048;
#pragma unroll
            for (int q = 0; q < 8; q++) {
                int i = base + t + q * 256;
                int j = i & 7, ln = (i >> 3) & 63, rem = i >> 9;
                int k32 = rem & 3, n16 = rem >> 2;
                int k = k32 * 32 + ((ln >> 4) << 3) + j;
                int n = n16 * 16 + (ln & 15);
                const float* Wr = (n < 15) ? W_I + n * 130
                                : (n < 30) ? W_R + (n - 15) * 130
                                           : W_sir + (n - 30) * 130;
                ushort h, l; split2(Wr[k], h, l);
                wtfh[i] = h; wtfl[i] = l;
            }
        }
    }
}

// ---- csrB: exclusive scan of 65536 counts, 64/thread ----
__global__ void csrB_kernel(const int* __restrict__ cnt, int* __restrict__ sbase) {
    __shared__ int ws1[16], ws2[16];
    int t = threadIdx.x, wv = t >> 6, ln = t & 63;
    int base = t * 64;
    int loc[64];
    int run = 0;
#pragma unroll
    for (int q = 0; q < 64; q++) { loc[q] = run; run += cnt[base + q]; }
    int s = run;
#pragma unroll
    for (int o = 1; o < 64; o <<= 1) { int u = __shfl_up(s, o, 64); if (ln >= o) s += u; }
    if (ln == 63) ws1[wv] = s;
    __syncthreads();
    if (t < 16) {
        int sv = ws1[t];
#pragma unroll
        for (int o = 1; o < 16; o <<= 1) { int u = __shfl_up(sv, o, 16); if (t >= o) sv += u; }
        ws2[t] = sv;
    }
    __syncthreads();
    int excl = (wv ? ws2[wv - 1] : 0) + s - run;
#pragma unroll
    for (int q = 0; q < 64; q++) sbase[base + q] = excl + loc[q];
}

// ---- csrC: slice scatter into packed ebuf (src | dst<<15) + alar_cast ----
__global__ void csrC_kernel(const int* __restrict__ ei, const int* __restrict__ sbase,
                            int* __restrict__ ebuf, const float* __restrict__ X,
                            const float* __restrict__ wf, ushort* __restrict__ Xbf,
                            float* __restrict__ al, float* __restrict__ ar) {
    int b = blockIdx.x, t = threadIdx.x;
    if (b < NSL) {
        __shared__ int cur[NB];
        cur[t] = sbase[t * NSL + b];
        __syncthreads();
        const int4* s4 = (const int4*)ei;
        const int4* d4 = (const int4*)(ei + NE);
        for (int i = t; i < ESL4; i += 256) {
            int4 sv = s4[b * ESL4 + i];
            int4 dv = d4[b * ESL4 + i];
            int p;
            p = atomicAdd(&cur[(unsigned)dv.x / RR], 1); ebuf[p] = sv.x | (dv.x << 15);
            p = atomicAdd(&cur[(unsigned)dv.y / RR], 1); ebuf[p] = sv.y | (dv.y << 15);
            p = atomicAdd(&cur[(unsigned)dv.z / RR], 1); ebuf[p] = sv.z | (dv.z << 15);
            p = atomicAdd(&cur[(unsigned)dv.w / RR], 1); ebuf[p] = sv.w | (dv.w << 15);
        }
    } else {
        __shared__ float ws[8][128];
        for (int i = t; i < 1024; i += 256) ws[i & 7][i >> 3] = wf[i];
        __syncthreads();
        int wv = t >> 6, ln = t & 63;
        int n = (b - NSL) * 4 + wv;
        float2 xv = *(const float2*)(X + (size_t)n * 128 + ln * 2);
        ushort2 ub;
        ub.x = f2bf_rne(xv.x);
        ub.y = f2bf_rne(xv.y);
        *(ushort2*)(Xbf + (size_t)n * 128 + ln * 2) = ub;
        float p[8];
#pragma unroll
        for (int o = 0; o < 8; o++) p[o] = xv.x * ws[o][ln * 2] + xv.y * ws[o][ln * 2 + 1];
#pragma unroll
        for (int off = 32; off > 0; off >>= 1)
#pragma unroll
            for (int o = 0; o < 8; o++) p[o] += __shfl_xor(p[o], off, 64);
        if (ln == 0) {
#pragma unroll
            for (int h = 0; h < 4; h++) {
                al[n * 4 + h] = p[h];
                ar[n * 4 + h] = p[4 + h];
            }
        }
    }
}

// ---- csrD: per-bucket local CSR build (packed ebuf) ----
__global__ void csrD_kernel(const int* __restrict__ ebuf, const int* __restrict__ sbase,
                            int* __restrict__ offs, int* __restrict__ csr_src) {
    __shared__ int hist[RR], lcur[RR];
    int b = blockIdx.x, t = threadIdx.x;
    int lo = b * RR;
    int Ra = min(RR, NN - lo);
    if (Ra <= 0) { if (b == 0 && t == 255) offs[NN] = NET; return; }
    int e0 = sbase[b * NSL];
    int e1 = (b < NB - 1) ? sbase[(b + 1) * NSL] : NE;
    int m = e1 - e0;
    for (int i = t; i < Ra; i += 256) hist[i] = 0;
    __syncthreads();
    for (int j = t; j < m; j += 256) atomicAdd(&hist[(ebuf[e0 + j] >> 15) - lo], 1);
    __syncthreads();
    if (t < 64) {
        int cbase = e0 + lo;
        int carry = 0;
#pragma unroll
        for (int c = 0; c < 2; c++) {
            int i = c * 64 + t;
            int v = (i < Ra) ? hist[i] + 1 : 0;   // +1 self-loop
            int s = v;
#pragma unroll
            for (int o = 1; o < 64; o <<= 1) { int u = __shfl_up(s, o, 64); if (t >= o) s += u; }
            if (i < Ra) {
                int off = cbase + carry + s - v;
                offs[lo + i] = off;
                lcur[i] = off;
            }
            carry += __shfl(s, 63, 64);
        }
    }
    if (b == 0 && t == 255) offs[NN] = NET;
    __syncthreads();
    for (int i = t; i < Ra; i += 256) csr_src[lcur[i] + hist[i]] = lo + i;  // self-loop last
    __syncthreads();
    for (int j = t; j < m; j += 256) {
        int p = ebuf[e0 + j];
        int pos = atomicAdd(&lcur[(p >> 15) - lo], 1);
        csr_src[pos] = p & 0x7FFF;
    }
}

// ---- GAT gather: wave/node, no-max softmax, 16 loads in flight ----
template <int H, bool FUSE>
__launch_bounds__(256)
__global__ void gat_gather_w(const ushort* __restrict__ X, const float* __restrict__ al,
                             const float* __restrict__ ar, const int* __restrict__ offs,
                             const int* __restrict__ csr, const float* __restrict__ bias,
                             void* __restrict__ outp) {
    int t = threadIdx.x;
    int wv = t >> 6, ln = t & 63;
    int n = blockIdx.x * 4 + wv;
    int e0 = offs[n], e1 = offs[n + 1];

    float arv[H], srun[H];
    f32x2 acc2[H];
#pragma unroll
    for (int h = 0; h < H; h++) {
        arv[h] = ar[n * H + h];
        srun[h] = 0.f;
        acc2[h][0] = 0.f; acc2[h][1] = 0.f;
    }
    const ushort* Xc = X + ln * 2;

    for (int base = e0; base < e1; base += 64) {
        int cnt = e1 - base; if (cnt > 64) cnt = 64;
        bool vld = ln < cnt;
        int src = vld ? csr[base + ln] : 0;
        float wgt[H];
        {
            float av[H];
            if (H == 4) {
                float4 a4 = *(const float4*)(al + (size_t)src * 4);
                av[0] = a4.x; av[H > 1 ? 1 : 0] = a4.y;
                av[H > 2 ? 2 : 0] = a4.z; av[H > 3 ? 3 : 0] = a4.w;
            } else {
                av[0] = al[src];
            }
#pragma unroll
            for (int h = 0; h < H; h++) {
                float lg = av[h] + arv[h];
                lg = lg > 0.f ? lg : 0.2f * lg;
                wgt[h] = vld ? __expf(lg) : 0.f;
            }
        }
        float ls[H];
#pragma unroll
        for (int h = 0; h < H; h++) ls[h] = wgt[h];
#pragma unroll
        for (int off = 32; off > 0; off >>= 1)
#pragma unroll
            for (int h = 0; h < H; h++) ls[h] += __shfl_xor(ls[h], off, 64);
#pragma unroll
        for (int h = 0; h < H; h++) srun[h] += ls[h];

        int k = 0;
        for (; k + 16 <= cnt; k += 16) {
            int s[16];
            unsigned u[16];
#pragma unroll
            for (int q = 0; q < 16; q++) s[q] = __builtin_amdgcn_readlane(src, k + q);
#pragma unroll
            for (int q = 0; q < 16; q++) u[q] = *(const unsigned*)(Xc + (size_t)s[q] * 128);
#pragma unroll
            for (int q = 0; q < 16; q++) {
                f32x2 xv;
                xv[0] = __uint_as_float(u[q] << 16);
                xv[1] = __uint_as_float(u[q] & 0xffff0000u);
#pragma unroll
                for (int h = 0; h < H; h++) {
                    float w = rlane(wgt[h], k + q);
                    f32x2 ww; ww[0] = w; ww[1] = w;
                    acc2[h] = __builtin_elementwise_fma(ww, xv, acc2[h]);
                }
            }
        }
        for (; k + 8 <= cnt; k += 8) {
            int s[8];
            unsigned u[8];
#pragma unroll
            for (int q = 0; q < 8; q++) s[q] = __builtin_amdgcn_readlane(src, k + q);
#pragma unroll
            for (int q = 0; q < 8; q++) u[q] = *(const unsigned*)(Xc + (size_t)s[q] * 128);
#pragma unroll
            for (int q = 0; q < 8; q++) {
                f32x2 xv;
                xv[0] = __uint_as_float(u[q] << 16);
                xv[1] = __uint_as_float(u[q] & 0xffff0000u);
#pragma unroll
                for (int h = 0; h < H; h++) {
                    float w = rlane(wgt[h], k + q);
                    f32x2 ww; ww[0] = w; ww[1] = w;
                    acc2[h] = __builtin_elementwise_fma(ww, xv, acc2[h]);
                }
            }
        }
        for (; k < cnt; k++) {
            int s0 = __builtin_amdgcn_readlane(src, k);
            unsigned u0 = *(const unsigned*)(Xc + (size_t)s0 * 128);
            f32x2 xv;
            xv[0] = __uint_as_float(u0 << 16);
            xv[1] = __uint_as_float(u0 & 0xffff0000u);
#pragma unroll
            for (int h = 0; h < H; h++) {
                float w = rlane(wgt[h], k);
                f32x2 ww; ww[0] = w; ww[1] = w;
                acc2[h] = __builtin_elementwise_fma(ww, xv, acc2[h]);
            }
        }
    }
    if (FUSE) {
        ushort* out = (ushort*)outp;
        float inv = 1.f / srun[0];
        float v0 = acc2[0][0] * inv + bias[ln * 2];
        float v1 = acc2[0][1] * inv + bias[ln * 2 + 1];
        v0 = v0 > 0.f ? v0 : __expf(v0) - 1.f;
        v1 = v1 > 0.f ? v1 : __expf(v1) - 1.f;
        ushort2 o;
        o.x = f2bf_rne(v0);
        o.y = f2bf_rne(v1);
        *(ushort2*)(out + (size_t)n * 128 + ln * 2) = o;
    } else {
        ushort* out = (ushort*)outp;
#pragma unroll
        for (int h = 0; h < H; h++) {
            float inv = 1.f / srun[h];
            ushort2 o;
            o.x = f2bf_rne(acc2[h][0] * inv);
            o.y = f2bf_rne(acc2[h][1] * inv);
            *(ushort2*)(out + (size_t)n * (H * 128) + h * 128 + ln * 2) = o;
        }
    }
}

// ---- MFMA GEMM: BM=64, 4 waves x (64 rows, 16 cols); B fragment-direct ----
template <int ACT, bool OUTBF, bool ALAR>
__launch_bounds__(256)
__global__ void gemm_fr(const ushort* __restrict__ A, const ushort* __restrict__ Bfh,
                        const ushort* __restrict__ Bfl, const float* __restrict__ bias,
                        void* __restrict__ Cptr, int M, int K, int lda, int ldc,
                        int zA, int zB, int zC, const float* __restrict__ w2f,
                        float* __restrict__ al2, float* __restrict__ ar2) {
    __shared__ ushort Ah[64 * 64];   // 8 KB
    __shared__ float s_w2f[ALAR ? 256 : 1][2];
    int tid = threadIdx.x;
    int z = blockIdx.z;
    int bm = blockIdx.x * 64;
    int ny = blockIdx.y * 64;
    int wid = tid >> 6, ln = tid & 63;
    int K32v = K >> 5;
    const bf16x8* BfhV = (const bf16x8*)Bfh;
    const bf16x8* BflV = (const bf16x8*)Bfl;
    f32x4 acc[4];
#pragma unroll
    for (int a = 0; a < 4; a++)
#pragma unroll
        for (int j = 0; j < 4; j++) acc[a][j] = 0.f;
    float p0a[4], p1a[4];
    bool do_alar = ALAR && blockIdx.y == 0;
    if (ALAR) {
#pragma unroll
        for (int i = 0; i < 4; i++) { p0a[i] = 0.f; p1a[i] = 0.f; }
        s_w2f[tid][0] = w2f[tid * 2];
        s_w2f[tid][1] = w2f[tid * 2 + 1];
        __syncthreads();
    }
    size_t abase = (size_t)z * zA;
    int ct = (z * zB + ny + wid * 16) >> 4;

    for (int k0 = 0; k0 < K; k0 += 64) {
#pragma unroll
        for (int i = 0; i < 4; i++) {
            int idx = tid + i * 256;
            int r = idx >> 4, c4 = (idx & 15) * 4;
            int gr = bm + r;
            ushort4 v = make_ushort4(0, 0, 0, 0);
            if (gr < M) v = *(const ushort4*)(A + abase + (size_t)gr * lda + k0 + c4);
            int ab = (r * 128 + c4 * 2) ^ ((r & 7) << 4);
            *(ushort4*)((char*)Ah + ab) = v;
            if (ALAR && do_alar) {
                int kk = k0 + c4;
                float x0 = bf2f(v.x), x1 = bf2f(v.y), x2 = bf2f(v.z), x3 = bf2f(v.w);
                p0a[i] = fmaf(x0, s_w2f[kk][0], p0a[i]);
                p0a[i] = fmaf(x1, s_w2f[kk + 1][0], p0a[i]);
                p0a[i] = fmaf(x2, s_w2f[kk + 2][0], p0a[i]);
                p0a[i] = fmaf(x3, s_w2f[kk + 3][0], p0a[i]);
                p1a[i] = fmaf(x0, s_w2f[kk][1], p1a[i]);
                p1a[i] = fmaf(x1, s_w2f[kk + 1][1], p1a[i]);
                p1a[i] = fmaf(x2, s_w2f[kk + 2][1], p1a[i]);
                p1a[i] = fmaf(x3, s_w2f[kk + 3][1], p1a[i]);
            }
        }
        __syncthreads();
#pragma unroll
        for (int ks = 0; ks < 2; ks++) {
            int k32 = (k0 >> 5) + ks;
            int kb = ks * 64 + (ln >> 4) * 16;
            size_t fb = (size_t)(ct * K32v + k32) * 64 + ln;
            bf16x8 bh = BfhV[fb];
            bf16x8 bl = BflV[fb];
#pragma unroll
            for (int mf = 0; mf < 4; mf++) {
                int r = mf * 16 + (ln & 15);
                int ab = (r * 128 + kb) ^ ((r & 7) << 4);
                bf16x8 ah = *(bf16x8*)((char*)Ah + ab);
                acc[mf] = __builtin_amdgcn_mfma_f32_16x16x32_bf16(ah, bh, acc[mf], 0, 0, 0);
                acc[mf] = __builtin_amdgcn_mfma_f32_16x16x32_bf16(ah, bl, acc[mf], 0, 0, 0);
            }
        }
        __syncthreads();
    }
    if (ALAR && do_alar) {
#pragma unroll
        for (int i = 0; i < 4; i++) {
            float p0 = p0a[i], p1 = p1a[i];
#pragma unroll
            for (int off = 8; off > 0; off >>= 1) {
                p0 += __shfl_xor(p0, off, 16);
                p1 += __shfl_xor(p1, off, 16);
            }
            if ((tid & 15) == 0) {
                int gr = bm + (tid >> 4) + i * 16;
                if (gr < M) { al2[gr] = p0; ar2[gr] = p1; }
            }
        }
    }
    float* Cf = (float*)Cptr;
    ushort* Cu = (ushort*)Cptr;
    int colL = ny + wid * 16 + (ln & 15);
#pragma unroll
    for (int mf = 0; mf < 4; mf++) {
#pragma unroll
        for (int j = 0; j < 4; j++) {
            int row = bm + mf * 16 + (ln >> 4) * 4 + j;
            if (row < M) {
                float v = acc[mf][j];
                if (ACT) {
                    v += bias[z * zC + colL];
                    v = v > 0.f ? v : (__expf(v) - 1.f);
                }
                size_t ci = (size_t)row * ldc + z * zC + colL;
                if (OUTBF) Cu[ci] = f2bf_rne(v);
                else       Cf[ci] = v;
            }
        }
    }
}

// ---- tail: GRU elementwise (reads gi bf16) + heads MFMA (frag-B) + SIR ----
__launch_bounds__(256)
__global__ void tail_kernel(const ushort* __restrict__ gi, const float* __restrict__ b_ih,
                            const float* __restrict__ b_hh, const ushort* __restrict__ wtfh,
                            const ushort* __restrict__ wtfl, const float* __restrict__ wc,
                            const float* __restrict__ wb, const float* __restrict__ cI,
                            const float* __restrict__ cR, const float* __restrict__ Npop,
                            const float* __restrict__ I0, const float* __restrict__ R0,
                            float* __restrict__ out_h, float* __restrict__ predI,
                            float* __restrict__ predR, float* __restrict__ phyI,
                            float* __restrict__ phyR) {
    __shared__ ushort As[64 * 128];   // 16 KB: swizzled h_bf tile
    __shared__ float s_ab[2][64];
    __shared__ float s_ci[64], s_cr[64];
    int t = threadIdx.x;
    int bm = blockIdx.x * 64;
    int wid = t >> 6, ln = t & 63;
    const bf16x8* WTh = (const bf16x8*)wtfh;
    const bf16x8* WTl = (const bf16x8*)wtfl;
    if (t < 64) {
        int n = bm + t;
        s_ci[t] = (n < NN) ? cI[n] : 0.f;
        s_cr[t] = (n < NN) ? cR[n] : 0.f;
    }
    // GRU elementwise: 2048 (row, c4) pieces
    for (int i = t; i < 2048; i += 256) {
        int r = i >> 5, c4 = (i & 31) * 4;
        int n = bm + r;
        ushort4 ua = make_ushort4(0, 0, 0, 0), ub = ua, uc = ua;
        if (n < NN) {
            const ushort* g = gi + (size_t)n * 384;
            ua = *(const ushort4*)(g + c4);
            ub = *(const ushort4*)(g + 128 + c4);
            uc = *(const ushort4*)(g + 256 + c4);
        }
        float gaa[4] = {bf2f(ua.x), bf2f(ua.y), bf2f(ua.z), bf2f(ua.w)};
        float gba[4] = {bf2f(ub.x), bf2f(ub.y), bf2f(ub.z), bf2f(ub.w)};
        float gca[4] = {bf2f(uc.x), bf2f(uc.y), bf2f(uc.z), bf2f(uc.w)};
        float hv[4];
#pragma unroll
        for (int q = 0; q < 4; q++) {
            int c = c4 + q;
            float rr = 1.f / (1.f + __expf(-(gaa[q] + b_ih[c] + b_hh[c])));
            float zz = 1.f / (1.f + __expf(-(gba[q] + b_ih[128 + c] + b_hh[128 + c])));
            float xx = gca[q] + b_ih[256 + c] + rr * b_hh[256 + c];
            xx = fminf(fmaxf(xx, -15.f), 15.f);
            float e2 = __expf(2.f * xx);
            hv[q] = (1.f - zz) * (e2 - 1.f) / (e2 + 1.f);
        }
        if (n < NN)
            *(float4*)(out_h + (size_t)n * 128 + c4) = make_float4(hv[0], hv[1], hv[2], hv[3]);
        ushort4 hb = make_ushort4(f2bf_rne(hv[0]), f2bf_rne(hv[1]), f2bf_rne(hv[2]), f2bf_rne(hv[3]));
        int ab = (r * 256 + c4 * 2) ^ ((r & 7) << 4);
        *(ushort4*)((char*)As + ab) = hb;
    }
    __syncthreads();
    // heads MFMA: wave wid -> rows wid*16..+15, 32 cols, B frags direct from global
    f32x4 acc2[2];
#pragma unroll
    for (int nf = 0; nf < 2; nf++)
#pragma unroll
        for (int j = 0; j < 4; j++) acc2[nf][j] = 0.f;
#pragma unroll
    for (int ks = 0; ks < 4; ks++) {
        int r = wid * 16 + (ln & 15);
        int abyte = (r * 256 + ks * 64 + (ln >> 4) * 16) ^ ((r & 7) << 4);
        bf16x8 ah = *(bf16x8*)((char*)As + abyte);
#pragma unroll
        for (int nf = 0; nf < 2; nf++) {
            size_t fb = (size_t)(nf * 4 + ks) * 64 + ln;
            bf16x8 bh = WTh[fb];
            bf16x8 bl = WTl[fb];
            acc2[nf] = __builtin_amdgcn_mfma_f32_16x16x32_bf16(ah, bh, acc2[nf], 0, 0, 0);
            acc2[nf] = __builtin_amdgcn_mfma_f32_16x16x32_bf16(ah, bl, acc2[nf], 0, 0, 0);
        }
    }
    // epilogue: bias + cI/cR cols, write preds, stash alpha/beta logits
#pragma unroll
    for (int nf = 0; nf < 2; nf++) {
        int col = nf * 16 + (ln & 15);
#pragma unroll
        for (int j = 0; j < 4; j++) {
            int rl = wid * 16 + (ln >> 4) * 4 + j;
            int n = bm + rl;
            float v = acc2[nf][j] + s_ci[rl] * wc[col * 2] + s_cr[rl] * wc[col * 2 + 1] + wb[col];
            if (n < NN) {
                if (col < 15)      predI[(size_t)n * 15 + col] = v;
                else if (col < 30) predR[(size_t)n * 15 + col - 15] = v;
            }
            if (col == 30) s_ab[0][rl] = v;
            if (col == 31) s_ab[1][rl] = v;
        }
    }
    __syncthreads();
    if (t < 64) {
        int n = bm + t;
        if (n < NN) {
            float alpha = 1.f / (1.f + __expf(-s_ab[0][t]));
            float beta  = 1.f / (1.f + __expf(-s_ab[1][t]));
            float Nv = Npop[n];
            float Iv = I0[n], Rv = R0[n];
            float SoN = (Nv - Iv - Rv) / Nv;
            for (int st = 0; st < 15; st++) {
                float dI = alpha * Iv * SoN - beta * Iv;
                float dR = beta * Iv;
                phyI[(size_t)n * 15 + st] = dI;
                phyR[(size_t)n * 15 + st] = dR;
                Iv += dI; Rv += dR;
            }
        }
    }
}

extern "C" void kernel_launch(void* const* d_in, const int* in_sizes, int n_in,
                              void* d_out, int out_size, void* d_ws, size_t ws_size,
                              hipStream_t stream) {
    const float* dynamic = (const float*)d_in[0];
    const int*   ei      = (const int*)d_in[1];
    const float* cI      = (const float*)d_in[2];
    const float* cR      = (const float*)d_in[3];
    const float* Npop    = (const float*)d_in[4];
    const float* I0      = (const float*)d_in[5];
    const float* R0      = (const float*)d_in[6];
    const float* W1      = (const float*)d_in[9];
    const float* a_src1  = (const float*)d_in[10];
    const float* a_dst1  = (const float*)d_in[11];
    const float* b1      = (const float*)d_in[12];
    const float* W2      = (const float*)d_in[13];
    const float* a_src2  = (const float*)d_in[14];
    const float* a_dst2  = (const float*)d_in[15];
    const float* b2      = (const float*)d_in[16];
    const float* W_ih    = (const float*)d_in[17];
    const float* b_ih    = (const float*)d_in[19];
    const float* b_hh    = (const float*)d_in[20];
    const float* W_I     = (const float*)d_in[21];
    const float* b_I     = (const float*)d_in[22];
    const float* W_R     = (const float*)d_in[23];
    const float* b_R     = (const float*)d_in[24];
    const float* W_sir   = (const float*)d_in[25];
    const float* b_sir   = (const float*)d_in[26];
    float* out = (float*)d_out;
    float* out_predI = out;
    float* out_predR = out + 300000;
    float* out_phyI  = out + 600000;
    float* out_phyR  = out + 900000;
    float* out_h     = out + 1200000;   // [20000][128] f32

    // ---- workspace layout ----
    int* wsi = (int*)d_ws;
    int* offs    = wsi;              // 20001 (pad 20096)
    int* csr_src = wsi + 20096;      // 660000 (pad 660096)
    int* cnt     = wsi + 680192;     // 65536
    int* sbase   = wsi + 745728;     // 65536
    float* fp = (float*)(wsi + 811264);
    float* w1f = fp; fp += 1152;     // 128*8
    float* w2f = fp; fp += 512;      // 256*2
    float* wc  = fp; fp += 64;
    float* wb  = fp; fp += 64;
    float* al1 = fp; fp += 80128;    // 20000*4
    float* ar1 = fp; fp += 80128;
    float* al2 = fp; fp += 20096;
    float* ar2 = fp; fp += 20096;
    // fragment-packed bf16 weights (ushort)
    ushort* wub  = (ushort*)fp; fp += 118784;  // 237568 ushorts
    ushort* w1fh = wub;            // 32768
    ushort* w1fl = wub + 32768;
    ushort* w2fh = wub + 65536;    // 32768
    ushort* w2fl = wub + 98304;
    ushort* w3fh = wub + 131072;   // 49152
    ushort* w3fl = wub + 180224;
    ushort* wtfh = wub + 229376;   // 4096
    ushort* wtfl = wub + 233472;
    ushort* dyn_bf = (ushort*)fp; fp += 1280000;   // 20000*128 bf16
    ushort* x1u = (ushort*)fp; fp += 2560000;      // [20000][256] bf16
    ushort* x2u = x1u;                             // [20000][128] bf16 (x1 dead)
    float* R  = fp; fp += 7680000;                 // ebuf / agg_bf / xl2_bf / gi_bf
    int* ebuf = (int*)R;                           // [640000] packed src|dst<<15
    ushort* agg_bf = (ushort*)R;                   // [20000][512] bf16
    ushort* xl2_bf = (ushort*)R;                   // [20000][128] bf16 (after agg dead)
    ushort* gi_bf  = (ushort*)R;                   // [20000][384] bf16 (after xl2 dead)

    // CSR build + weight prep (packs parallelized over 58 blocks)
    csrA_kernel<<<NSL + 3 + 58, 256, 0, stream>>>(ei, cnt, W1, a_src1, a_dst1, w1f,
                                                  W2, a_src2, a_dst2, w2f, W_ih,
                                                  W_I, b_I, W_R, b_R, W_sir, b_sir,
                                                  w1fh, w1fl, w2fh, w2fl, w3fh, w3fl,
                                                  wtfh, wtfl, wc, wb);
    csrB_kernel<<<1, 1024, 0, stream>>>(cnt, sbase);
    csrC_kernel<<<NSL + 5000, 256, 0, stream>>>(ei, sbase, ebuf, dynamic, w1f,
                                                dyn_bf, al1, ar1);
    csrD_kernel<<<NB, 256, 0, stream>>>(ebuf, sbase, offs, csr_src);

    // GAT layer 1
    gat_gather_w<4, false><<<5000, 256, 0, stream>>>(dyn_bf, al1, ar1, offs, csr_src, nullptr, agg_bf);
    gemm_fr<1, true, false><<<dim3(313, 1, 4), 256, 0, stream>>>(
        agg_bf, w1fh, w1fl, b1, x1u, NN, 128, 512, 256, 128, 64, 64,
        nullptr, nullptr, nullptr);

    // GAT layer 2 (al2/ar2 fused into GEMM via w2f fold, y==0 blocks only)
    gemm_fr<0, true, true><<<dim3(313, 2, 1), 256, 0, stream>>>(
        x1u, w2fh, w2fl, nullptr, xl2_bf, NN, 256, 256, 128, 0, 0, 0,
        w2f, al2, ar2);
    gat_gather_w<1, true><<<5000, 256, 0, stream>>>(xl2_bf, al2, ar2, offs, csr_src, b2, x2u);

    // gi = x2 @ W_ih^T (N=384 via y x z), bf16 output
    gemm_fr<0, true, false><<<dim3(313, 2, 3), 256, 0, stream>>>(
        x2u, w3fh, w3fl, nullptr, gi_bf, NN, 128, 128, 384, 0, 128, 128,
        nullptr, nullptr, nullptr);

    // GRU + heads + SIR
    tail_kernel<<<313, 256, 0, stream>>>(gi_bf, b_ih, b_hh, wtfh, wtfl, wc, wb,
                                         cI, cR, Npop, I0, R0, out_h,
                                         out_predI, out_predR, out_phyI, out_phyR);
}

// Round 16
// 171.155 us; speedup vs baseline: 1.1226x; 1.0144x over previous
//
#include <hip/hip_runtime.h>

#define NN 20000
#define NE 640000
#define NET (NE + NN)   // 660000 edges incl. self-loops
#define NB 256          // dst buckets
#define RR 79           // nodes per bucket (ceil 20000/256)
#define NSL 256         // edge slices
#define ESL4 625        // int4 per slice (2500 edges)

typedef __attribute__((ext_vector_type(8))) short bf16x8;
typedef __attribute__((ext_vector_type(4))) float f32x4;
typedef __attribute__((ext_vector_type(2))) float f32x2;

__device__ inline ushort f2bf_rne(float x) {
    unsigned u = __float_as_uint(x);
    return (ushort)((u + 0x7FFFu + ((u >> 16) & 1u)) >> 16);
}
__device__ inline float bf2f(ushort u) {
    return __uint_as_float(((unsigned)u) << 16);
}
__device__ inline void split2(float x, ushort& hi, ushort& lo) {
    unsigned u = __float_as_uint(x);
    unsigned r = (u + 0x7FFFu + ((u >> 16) & 1u)) & 0xFFFF0000u;  // RNE to bf16
    hi = (ushort)(r >> 16);
    lo = f2bf_rne(x - __uint_as_float(r));   // x - hi is exact
}
__device__ inline float rlane(float x, int k) {
    return __int_as_float(__builtin_amdgcn_readlane(__float_as_int(x), k));
}

// Fragment layout for B[K][N]: vec-index (ctile*K32 + k32)*64 + ln holds bf16x8
// with element j = B[k32*32 + (ln>>4)*8 + j][ctile*16 + (ln&15)].

// ---- csrA: per-slice bucket histogram + folds + PARALLEL fragment packs ----
__global__ void csrA_kernel(const int* __restrict__ ei, ushort* __restrict__ cnt,
                            const float* __restrict__ W1, const float* __restrict__ as1,
                            const float* __restrict__ ad1, float* __restrict__ w1f,
                            const float* __restrict__ W2, const float* __restrict__ as2,
                            const float* __restrict__ ad2, float* __restrict__ w2f,
                            const float* __restrict__ W_ih,
                            const float* __restrict__ W_I, const float* __restrict__ b_I,
                            const float* __restrict__ W_R, const float* __restrict__ b_R,
                            const float* __restrict__ W_sir, const float* __restrict__ b_sir,
                            ushort* __restrict__ w1fh, ushort* __restrict__ w1fl,
                            ushort* __restrict__ w2fh, ushort* __restrict__ w2fl,
                            ushort* __restrict__ w3fh, ushort* __restrict__ w3fl,
                            ushort* __restrict__ wtfh, ushort* __restrict__ wtfl,
                            float* __restrict__ wc, float* __restrict__ wb) {
    int b = blockIdx.x, t = threadIdx.x;
    if (b < NSL) {
        __shared__ int h[NB];
        h[t] = 0;
        __syncthreads();
        const int4* d4 = (const int4*)(ei + NE);
        for (int i = t; i < ESL4; i += 256) {
            int4 d = d4[b * ESL4 + i];
            atomicAdd(&h[(unsigned)d.x / RR], 1);
            atomicAdd(&h[(unsigned)d.y / RR], 1);
            atomicAdd(&h[(unsigned)d.z / RR], 1);
            atomicAdd(&h[(unsigned)d.w / RR], 1);
        }
        __syncthreads();
        cnt[t * NSL + b] = (ushort)h[t];   // bucket-major
    } else if (b == NSL) {
        if (t < 128) {
            int k = t;
#pragma unroll
            for (int hh = 0; hh < 4; hh++) {
                float s1 = 0.f, s2 = 0.f;
                for (int c = 0; c < 64; c++) {
                    float w = W1[k * 256 + hh * 64 + c];
                    s1 += w * as1[hh * 64 + c];
                    s2 += w * ad1[hh * 64 + c];
                }
                w1f[k * 8 + hh] = s1;
                w1f[k * 8 + 4 + hh] = s2;
            }
        }
    } else if (b == NSL + 1) {
        int k = t;
        float s1 = 0.f, s2 = 0.f;
        for (int c = 0; c < 128; c++) {
            float w = W2[k * 128 + c];
            s1 += w * as2[c];
            s2 += w * ad2[c];
        }
        w2f[k * 2] = s1;
        w2f[k * 2 + 1] = s2;
    } else if (b == NSL + 2) {
        if (t < 32) {
            int p = t;
            const float* Wr = (p < 15) ? W_I + p * 130
                            : (p < 30) ? W_R + (p - 15) * 130
                                       : W_sir + (p - 30) * 130;
            wc[p * 2] = Wr[128];
            wc[p * 2 + 1] = Wr[129];
            wb[p] = (p < 15) ? b_I[p] : (p < 30) ? b_R[p - 15] : b_sir[p - 30];
        }
    } else {
        int pb = b - (NSL + 3);   // 0..57
        if (pb < 16) {
            // W1 [K=128][N=256]: K32=4
            int base = pb * 2048;
#pragma unroll
            for (int q = 0; q < 8; q++) {
                int i = base + t + q * 256;
                int j = i & 7, ln = (i >> 3) & 63, rem = i >> 9;
                int k32 = rem & 3, n16 = rem >> 2;
                int k = k32 * 32 + ((ln >> 4) << 3) + j;
                int n = n16 * 16 + (ln & 15);
                ushort h, l; split2(W1[k * 256 + n], h, l);
                w1fh[i] = h; w1fl[i] = l;
            }
        } else if (pb < 32) {
            // W2 [K=256][N=128]: K32=8
            int base = (pb - 16) * 2048;
#pragma unroll
            for (int q = 0; q < 8; q++) {
                int i = base + t + q * 256;
                int j = i & 7, ln = (i >> 3) & 63, rem = i >> 9;
                int k32 = rem & 7, n16 = rem >> 3;
                int k = k32 * 32 + ((ln >> 4) << 3) + j;
                int n = n16 * 16 + (ln & 15);
                ushort h, l; split2(W2[k * 128 + n], h, l);
                w2fh[i] = h; w2fl[i] = l;
            }
        } else if (pb < 56) {
            // W_ih^T [K=128][N=384] (B[k][n] = W_ih[n*128+k]): K32=4
            int base = (pb - 32) * 2048;
#pragma unroll
            for (int q = 0; q < 8; q++) {
                int i = base + t + q * 256;
                int j = i & 7, ln = (i >> 3) & 63, rem = i >> 9;
                int k32 = rem & 3, n16 = rem >> 2;
                int k = k32 * 32 + ((ln >> 4) << 3) + j;
                int n = n16 * 16 + (ln & 15);
                ushort h, l; split2(W_ih[n * 128 + k], h, l);
                w3fh[i] = h; w3fl[i] = l;
            }
        } else {
            // heads Wt (N=32, K=128): K32=4
            int base = (pb - 56) * 2048;
#pragma unroll
            for (int q = 0; q < 8; q++) {
                int i = base + t + q * 256;
                int j = i & 7, ln = (i >> 3) & 63, rem = i >> 9;
                int k32 = rem & 3, n16 = rem >> 2;
                int k = k32 * 32 + ((ln >> 4) << 3) + j;
                int n = n16 * 16 + (ln & 15);
                const float* Wr = (n < 15) ? W_I + n * 130
                                : (n < 30) ? W_R + (n - 15) * 130
                                           : W_sir + (n - 30) * 130;
                ushort h, l; split2(Wr[k], h, l);
                wtfh[i] = h; wtfl[i] = l;
            }
        }
    }
}

// ---- csrB: exclusive scan of 65536 ushort counts, 64/thread ----
__global__ void csrB_kernel(const ushort* __restrict__ cnt, int* __restrict__ sbase) {
    __shared__ int ws1[16], ws2[16];
    int t = threadIdx.x, wv = t >> 6, ln = t & 63;
    int base = t * 64;
    int loc[64];
    int run = 0;
    const ushort4* c4 = (const ushort4*)(cnt + base);
#pragma unroll
    for (int q = 0; q < 16; q++) {
        ushort4 v = c4[q];
        loc[q * 4 + 0] = run; run += v.x;
        loc[q * 4 + 1] = run; run += v.y;
        loc[q * 4 + 2] = run; run += v.z;
        loc[q * 4 + 3] = run; run += v.w;
    }
    int s = run;
#pragma unroll
    for (int o = 1; o < 64; o <<= 1) { int u = __shfl_up(s, o, 64); if (ln >= o) s += u; }
    if (ln == 63) ws1[wv] = s;
    __syncthreads();
    if (t < 16) {
        int sv = ws1[t];
#pragma unroll
        for (int o = 1; o < 16; o <<= 1) { int u = __shfl_up(sv, o, 16); if (t >= o) sv += u; }
        ws2[t] = sv;
    }
    __syncthreads();
    int excl = (wv ? ws2[wv - 1] : 0) + s - run;
#pragma unroll
    for (int q = 0; q < 64; q++) sbase[base + q] = excl + loc[q];
}

// ---- csrC: slice scatter into packed ebuf (src | dst<<15) + alar_cast ----
__global__ void csrC_kernel(const int* __restrict__ ei, const int* __restrict__ sbase,
                            int* __restrict__ ebuf, const float* __restrict__ X,
                            const float* __restrict__ wf, ushort* __restrict__ Xbf,
                            float* __restrict__ al, float* __restrict__ ar) {
    int b = blockIdx.x, t = threadIdx.x;
    if (b < NSL) {
        __shared__ int cur[NB];
        cur[t] = sbase[t * NSL + b];
        __syncthreads();
        const int4* s4 = (const int4*)ei;
        const int4* d4 = (const int4*)(ei + NE);
        for (int i = t; i < ESL4; i += 256) {
            int4 sv = s4[b * ESL4 + i];
            int4 dv = d4[b * ESL4 + i];
            int p;
            p = atomicAdd(&cur[(unsigned)dv.x / RR], 1); ebuf[p] = sv.x | (dv.x << 15);
            p = atomicAdd(&cur[(unsigned)dv.y / RR], 1); ebuf[p] = sv.y | (dv.y << 15);
            p = atomicAdd(&cur[(unsigned)dv.z / RR], 1); ebuf[p] = sv.z | (dv.z << 15);
            p = atomicAdd(&cur[(unsigned)dv.w / RR], 1); ebuf[p] = sv.w | (dv.w << 15);
        }
    } else {
        __shared__ float ws[8][128];
        for (int i = t; i < 1024; i += 256) ws[i & 7][i >> 3] = wf[i];
        __syncthreads();
        int wv = t >> 6, ln = t & 63;
        int n = (b - NSL) * 4 + wv;
        float2 xv = *(const float2*)(X + (size_t)n * 128 + ln * 2);
        ushort2 ub;
        ub.x = f2bf_rne(xv.x);
        ub.y = f2bf_rne(xv.y);
        *(ushort2*)(Xbf + (size_t)n * 128 + ln * 2) = ub;
        float p[8];
#pragma unroll
        for (int o = 0; o < 8; o++) p[o] = xv.x * ws[o][ln * 2] + xv.y * ws[o][ln * 2 + 1];
#pragma unroll
        for (int off = 32; off > 0; off >>= 1)
#pragma unroll
            for (int o = 0; o < 8; o++) p[o] += __shfl_xor(p[o], off, 64);
        if (ln == 0) {
#pragma unroll
            for (int h = 0; h < 4; h++) {
                al[n * 4 + h] = p[h];
                ar[n * 4 + h] = p[4 + h];
            }
        }
    }
}

// ---- csrD: per-bucket local CSR build (packed ebuf) ----
__global__ void csrD_kernel(const int* __restrict__ ebuf, const int* __restrict__ sbase,
                            int* __restrict__ offs, int* __restrict__ csr_src) {
    __shared__ int hist[RR], lcur[RR];
    int b = blockIdx.x, t = threadIdx.x;
    int lo = b * RR;
    int Ra = min(RR, NN - lo);
    if (Ra <= 0) { if (b == 0 && t == 255) offs[NN] = NET; return; }
    int e0 = sbase[b * NSL];
    int e1 = (b < NB - 1) ? sbase[(b + 1) * NSL] : NE;
    int m = e1 - e0;
    for (int i = t; i < Ra; i += 256) hist[i] = 0;
    __syncthreads();
    for (int j = t; j < m; j += 256) atomicAdd(&hist[(ebuf[e0 + j] >> 15) - lo], 1);
    __syncthreads();
    if (t < 64) {
        int cbase = e0 + lo;
        int carry = 0;
#pragma unroll
        for (int c = 0; c < 2; c++) {
            int i = c * 64 + t;
            int v = (i < Ra) ? hist[i] + 1 : 0;   // +1 self-loop
            int s = v;
#pragma unroll
            for (int o = 1; o < 64; o <<= 1) { int u = __shfl_up(s, o, 64); if (t >= o) s += u; }
            if (i < Ra) {
                int off = cbase + carry + s - v;
                offs[lo + i] = off;
                lcur[i] = off;
            }
            carry += __shfl(s, 63, 64);
        }
    }
    if (b == 0 && t == 255) offs[NN] = NET;
    __syncthreads();
    for (int i = t; i < Ra; i += 256) csr_src[lcur[i] + hist[i]] = lo + i;  // self-loop last
    __syncthreads();
    for (int j = t; j < m; j += 256) {
        int p = ebuf[e0 + j];
        int pos = atomicAdd(&lcur[(p >> 15) - lo], 1);
        csr_src[pos] = p & 0x7FFF;
    }
}

// ---- GAT gather: wave/node, no-max softmax, 16 loads in flight ----
template <int H, bool FUSE>
__launch_bounds__(256)
__global__ void gat_gather_w(const ushort* __restrict__ X, const float* __restrict__ al,
                             const float* __restrict__ ar, const int* __restrict__ offs,
                             const int* __restrict__ csr, const float* __restrict__ bias,
                             void* __restrict__ outp) {
    int t = threadIdx.x;
    int wv = t >> 6, ln = t & 63;
    int n = blockIdx.x * 4 + wv;
    int e0 = offs[n], e1 = offs[n + 1];

    float arv[H], srun[H];
    f32x2 acc2[H];
#pragma unroll
    for (int h = 0; h < H; h++) {
        arv[h] = ar[n * H + h];
        srun[h] = 0.f;
        acc2[h][0] = 0.f; acc2[h][1] = 0.f;
    }
    const ushort* Xc = X + ln * 2;

    for (int base = e0; base < e1; base += 64) {
        int cnt = e1 - base; if (cnt > 64) cnt = 64;
        bool vld = ln < cnt;
        int src = vld ? csr[base + ln] : 0;
        float wgt[H];
        {
            float av[H];
            if (H == 4) {
                float4 a4 = *(const float4*)(al + (size_t)src * 4);
                av[0] = a4.x; av[H > 1 ? 1 : 0] = a4.y;
                av[H > 2 ? 2 : 0] = a4.z; av[H > 3 ? 3 : 0] = a4.w;
            } else {
                av[0] = al[src];
            }
#pragma unroll
            for (int h = 0; h < H; h++) {
                float lg = av[h] + arv[h];
                lg = lg > 0.f ? lg : 0.2f * lg;
                wgt[h] = vld ? __expf(lg) : 0.f;
            }
        }
        float ls[H];
#pragma unroll
        for (int h = 0; h < H; h++) ls[h] = wgt[h];
#pragma unroll
        for (int off = 32; off > 0; off >>= 1)
#pragma unroll
            for (int h = 0; h < H; h++) ls[h] += __shfl_xor(ls[h], off, 64);
#pragma unroll
        for (int h = 0; h < H; h++) srun[h] += ls[h];

        int k = 0;
        for (; k + 16 <= cnt; k += 16) {
            int s[16];
            unsigned u[16];
#pragma unroll
            for (int q = 0; q < 16; q++) s[q] = __builtin_amdgcn_readlane(src, k + q);
#pragma unroll
            for (int q = 0; q < 16; q++) u[q] = *(const unsigned*)(Xc + (size_t)s[q] * 128);
#pragma unroll
            for (int q = 0; q < 16; q++) {
                f32x2 xv;
                xv[0] = __uint_as_float(u[q] << 16);
                xv[1] = __uint_as_float(u[q] & 0xffff0000u);
#pragma unroll
                for (int h = 0; h < H; h++) {
                    float w = rlane(wgt[h], k + q);
                    f32x2 ww; ww[0] = w; ww[1] = w;
                    acc2[h] = __builtin_elementwise_fma(ww, xv, acc2[h]);
                }
            }
        }
        for (; k + 8 <= cnt; k += 8) {
            int s[8];
            unsigned u[8];
#pragma unroll
            for (int q = 0; q < 8; q++) s[q] = __builtin_amdgcn_readlane(src, k + q);
#pragma unroll
            for (int q = 0; q < 8; q++) u[q] = *(const unsigned*)(Xc + (size_t)s[q] * 128);
#pragma unroll
            for (int q = 0; q < 8; q++) {
                f32x2 xv;
                xv[0] = __uint_as_float(u[q] << 16);
                xv[1] = __uint_as_float(u[q] & 0xffff0000u);
#pragma unroll
                for (int h = 0; h < H; h++) {
                    float w = rlane(wgt[h], k + q);
                    f32x2 ww; ww[0] = w; ww[1] = w;
                    acc2[h] = __builtin_elementwise_fma(ww, xv, acc2[h]);
                }
            }
        }
        for (; k < cnt; k++) {
            int s0 = __builtin_amdgcn_readlane(src, k);
            unsigned u0 = *(const unsigned*)(Xc + (size_t)s0 * 128);
            f32x2 xv;
            xv[0] = __uint_as_float(u0 << 16);
            xv[1] = __uint_as_float(u0 & 0xffff0000u);
#pragma unroll
            for (int h = 0; h < H; h++) {
                float w = rlane(wgt[h], k);
                f32x2 ww; ww[0] = w; ww[1] = w;
                acc2[h] = __builtin_elementwise_fma(ww, xv, acc2[h]);
            }
        }
    }
    if (FUSE) {
        ushort* out = (ushort*)outp;
        float inv = 1.f / srun[0];
        float v0 = acc2[0][0] * inv + bias[ln * 2];
        float v1 = acc2[0][1] * inv + bias[ln * 2 + 1];
        v0 = v0 > 0.f ? v0 : __expf(v0) - 1.f;
        v1 = v1 > 0.f ? v1 : __expf(v1) - 1.f;
        ushort2 o;
        o.x = f2bf_rne(v0);
        o.y = f2bf_rne(v1);
        *(ushort2*)(out + (size_t)n * 128 + ln * 2) = o;
    } else {
        ushort* out = (ushort*)outp;
#pragma unroll
        for (int h = 0; h < H; h++) {
            float inv = 1.f / srun[h];
            ushort2 o;
            o.x = f2bf_rne(acc2[h][0] * inv);
            o.y = f2bf_rne(acc2[h][1] * inv);
            *(ushort2*)(out + (size_t)n * (H * 128) + h * 128 + ln * 2) = o;
        }
    }
}

// ---- MFMA GEMM: BM=64, 4 waves x (64 rows, NF*16 cols); B fragment-direct ----
template <int ACT, bool OUTBF, bool ALAR, int NF>
__launch_bounds__(256)
__global__ void gemm_fr(const ushort* __restrict__ A, const ushort* __restrict__ Bfh,
                        const ushort* __restrict__ Bfl, const float* __restrict__ bias,
                        void* __restrict__ Cptr, int M, int K, int lda, int ldc,
                        int zA, int zB, int zC, const float* __restrict__ w2f,
                        float* __restrict__ al2, float* __restrict__ ar2) {
    __shared__ ushort Ah[64 * 64];   // 8 KB
    __shared__ float s_w2f[ALAR ? 256 : 1][2];
    int tid = threadIdx.x;
    int z = blockIdx.z;
    int bm = blockIdx.x * 64;
    int ny = blockIdx.y * (64 * NF);
    int wid = tid >> 6, ln = tid & 63;
    int K32v = K >> 5;
    const bf16x8* BfhV = (const bf16x8*)Bfh;
    const bf16x8* BflV = (const bf16x8*)Bfl;
    f32x4 acc[4][NF];
#pragma unroll
    for (int a = 0; a < 4; a++)
#pragma unroll
        for (int nf = 0; nf < NF; nf++)
#pragma unroll
            for (int j = 0; j < 4; j++) acc[a][nf][j] = 0.f;
    float p0a[4], p1a[4];
    bool do_alar = ALAR && blockIdx.y == 0;
    if (ALAR) {
#pragma unroll
        for (int i = 0; i < 4; i++) { p0a[i] = 0.f; p1a[i] = 0.f; }
        s_w2f[tid][0] = w2f[tid * 2];
        s_w2f[tid][1] = w2f[tid * 2 + 1];
        __syncthreads();
    }
    size_t abase = (size_t)z * zA;
    int ct[NF];
#pragma unroll
    for (int nf = 0; nf < NF; nf++)
        ct[nf] = (z * zB + ny + wid * (16 * NF) + nf * 16) >> 4;

    for (int k0 = 0; k0 < K; k0 += 64) {
#pragma unroll
        for (int i = 0; i < 4; i++) {
            int idx = tid + i * 256;
            int r = idx >> 4, c4 = (idx & 15) * 4;
            int gr = bm + r;
            ushort4 v = make_ushort4(0, 0, 0, 0);
            if (gr < M) v = *(const ushort4*)(A + abase + (size_t)gr * lda + k0 + c4);
            int ab = (r * 128 + c4 * 2) ^ ((r & 7) << 4);
            *(ushort4*)((char*)Ah + ab) = v;
            if (ALAR && do_alar) {
                int kk = k0 + c4;
                float x0 = bf2f(v.x), x1 = bf2f(v.y), x2 = bf2f(v.z), x3 = bf2f(v.w);
                p0a[i] = fmaf(x0, s_w2f[kk][0], p0a[i]);
                p0a[i] = fmaf(x1, s_w2f[kk + 1][0], p0a[i]);
                p0a[i] = fmaf(x2, s_w2f[kk + 2][0], p0a[i]);
                p0a[i] = fmaf(x3, s_w2f[kk + 3][0], p0a[i]);
                p1a[i] = fmaf(x0, s_w2f[kk][1], p1a[i]);
                p1a[i] = fmaf(x1, s_w2f[kk + 1][1], p1a[i]);
                p1a[i] = fmaf(x2, s_w2f[kk + 2][1], p1a[i]);
                p1a[i] = fmaf(x3, s_w2f[kk + 3][1], p1a[i]);
            }
        }
        __syncthreads();
#pragma unroll
        for (int ks = 0; ks < 2; ks++) {
            int k32 = (k0 >> 5) + ks;
            int kb = ks * 64 + (ln >> 4) * 16;
#pragma unroll
            for (int nf = 0; nf < NF; nf++) {
                size_t fb = (size_t)(ct[nf] * K32v + k32) * 64 + ln;
                bf16x8 bh = BfhV[fb];
                bf16x8 bl = BflV[fb];
#pragma unroll
                for (int mf = 0; mf < 4; mf++) {
                    int r = mf * 16 + (ln & 15);
                    int ab = (r * 128 + kb) ^ ((r & 7) << 4);
                    bf16x8 ah = *(bf16x8*)((char*)Ah + ab);
                    acc[mf][nf] = __builtin_amdgcn_mfma_f32_16x16x32_bf16(ah, bh, acc[mf][nf], 0, 0, 0);
                    acc[mf][nf] = __builtin_amdgcn_mfma_f32_16x16x32_bf16(ah, bl, acc[mf][nf], 0, 0, 0);
                }
            }
        }
        __syncthreads();
    }
    if (ALAR && do_alar) {
#pragma unroll
        for (int i = 0; i < 4; i++) {
            float p0 = p0a[i], p1 = p1a[i];
#pragma unroll
            for (int off = 8; off > 0; off >>= 1) {
                p0 += __shfl_xor(p0, off, 16);
                p1 += __shfl_xor(p1, off, 16);
            }
            if ((tid & 15) == 0) {
                int gr = bm + (tid >> 4) + i * 16;
                if (gr < M) { al2[gr] = p0; ar2[gr] = p1; }
            }
        }
    }
    float* Cf = (float*)Cptr;
    ushort* Cu = (ushort*)Cptr;
#pragma unroll
    for (int nf = 0; nf < NF; nf++) {
        int colL = ny + wid * (16 * NF) + nf * 16 + (ln & 15);
#pragma unroll
        for (int mf = 0; mf < 4; mf++) {
#pragma unroll
            for (int j = 0; j < 4; j++) {
                int row = bm + mf * 16 + (ln >> 4) * 4 + j;
                if (row < M) {
                    float v = acc[mf][nf][j];
                    if (ACT) {
                        v += bias[z * zC + colL];
                        v = v > 0.f ? v : (__expf(v) - 1.f);
                    }
                    size_t ci = (size_t)row * ldc + z * zC + colL;
                    if (OUTBF) Cu[ci] = f2bf_rne(v);
                    else       Cf[ci] = v;
                }
            }
        }
    }
}

// ---- tail: GRU elementwise (reads gi bf16) + heads MFMA (frag-B) + SIR ----
__launch_bounds__(256)
__global__ void tail_kernel(const ushort* __restrict__ gi, const float* __restrict__ b_ih,
                            const float* __restrict__ b_hh, const ushort* __restrict__ wtfh,
                            const ushort* __restrict__ wtfl, const float* __restrict__ wc,
                            const float* __restrict__ wb, const float* __restrict__ cI,
                            const float* __restrict__ cR, const float* __restrict__ Npop,
                            const float* __restrict__ I0, const float* __restrict__ R0,
                            float* __restrict__ out_h, float* __restrict__ predI,
                            float* __restrict__ predR, float* __restrict__ phyI,
                            float* __restrict__ phyR) {
    __shared__ ushort As[64 * 128];   // 16 KB: swizzled h_bf tile
    __shared__ float s_ab[2][64];
    __shared__ float s_ci[64], s_cr[64];
    int t = threadIdx.x;
    int bm = blockIdx.x * 64;
    int wid = t >> 6, ln = t & 63;
    const bf16x8* WTh = (const bf16x8*)wtfh;
    const bf16x8* WTl = (const bf16x8*)wtfl;
    if (t < 64) {
        int n = bm + t;
        s_ci[t] = (n < NN) ? cI[n] : 0.f;
        s_cr[t] = (n < NN) ? cR[n] : 0.f;
    }
    // GRU elementwise: 2048 (row, c4) pieces
    for (int i = t; i < 2048; i += 256) {
        int r = i >> 5, c4 = (i & 31) * 4;
        int n = bm + r;
        ushort4 ua = make_ushort4(0, 0, 0, 0), ub = ua, uc = ua;
        if (n < NN) {
            const ushort* g = gi + (size_t)n * 384;
            ua = *(const ushort4*)(g + c4);
            ub = *(const ushort4*)(g + 128 + c4);
            uc = *(const ushort4*)(g + 256 + c4);
        }
        float gaa[4] = {bf2f(ua.x), bf2f(ua.y), bf2f(ua.z), bf2f(ua.w)};
        float gba[4] = {bf2f(ub.x), bf2f(ub.y), bf2f(ub.z), bf2f(ub.w)};
        float gca[4] = {bf2f(uc.x), bf2f(uc.y), bf2f(uc.z), bf2f(uc.w)};
        float hv[4];
#pragma unroll
        for (int q = 0; q < 4; q++) {
            int c = c4 + q;
            float rr = 1.f / (1.f + __expf(-(gaa[q] + b_ih[c] + b_hh[c])));
            float zz = 1.f / (1.f + __expf(-(gba[q] + b_ih[128 + c] + b_hh[128 + c])));
            float xx = gca[q] + b_ih[256 + c] + rr * b_hh[256 + c];
            xx = fminf(fmaxf(xx, -15.f), 15.f);
            float e2 = __expf(2.f * xx);
            hv[q] = (1.f - zz) * (e2 - 1.f) / (e2 + 1.f);
        }
        if (n < NN)
            *(float4*)(out_h + (size_t)n * 128 + c4) = make_float4(hv[0], hv[1], hv[2], hv[3]);
        ushort4 hb = make_ushort4(f2bf_rne(hv[0]), f2bf_rne(hv[1]), f2bf_rne(hv[2]), f2bf_rne(hv[3]));
        int ab = (r * 256 + c4 * 2) ^ ((r & 7) << 4);
        *(ushort4*)((char*)As + ab) = hb;
    }
    __syncthreads();
    // heads MFMA: wave wid -> rows wid*16..+15, 32 cols, B frags direct from global
    f32x4 acc2[2];
#pragma unroll
    for (int nf = 0; nf < 2; nf++)
#pragma unroll
        for (int j = 0; j < 4; j++) acc2[nf][j] = 0.f;
#pragma unroll
    for (int ks = 0; ks < 4; ks++) {
        int r = wid * 16 + (ln & 15);
        int abyte = (r * 256 + ks * 64 + (ln >> 4) * 16) ^ ((r & 7) << 4);
        bf16x8 ah = *(bf16x8*)((char*)As + abyte);
#pragma unroll
        for (int nf = 0; nf < 2; nf++) {
            size_t fb = (size_t)(nf * 4 + ks) * 64 + ln;
            bf16x8 bh = WTh[fb];
            bf16x8 bl = WTl[fb];
            acc2[nf] = __builtin_amdgcn_mfma_f32_16x16x32_bf16(ah, bh, acc2[nf], 0, 0, 0);
            acc2[nf] = __builtin_amdgcn_mfma_f32_16x16x32_bf16(ah, bl, acc2[nf], 0, 0, 0);
        }
    }
    // epilogue: bias + cI/cR cols, write preds, stash alpha/beta logits
#pragma unroll
    for (int nf = 0; nf < 2; nf++) {
        int col = nf * 16 + (ln & 15);
#pragma unroll
        for (int j = 0; j < 4; j++) {
            int rl = wid * 16 + (ln >> 4) * 4 + j;
            int n = bm + rl;
            float v = acc2[nf][j] + s_ci[rl] * wc[col * 2] + s_cr[rl] * wc[col * 2 + 1] + wb[col];
            if (n < NN) {
                if (col < 15)      predI[(size_t)n * 15 + col] = v;
                else if (col < 30) predR[(size_t)n * 15 + col - 15] = v;
            }
            if (col == 30) s_ab[0][rl] = v;
            if (col == 31) s_ab[1][rl] = v;
        }
    }
    __syncthreads();
    if (t < 64) {
        int n = bm + t;
        if (n < NN) {
            float alpha = 1.f / (1.f + __expf(-s_ab[0][t]));
            float beta  = 1.f / (1.f + __expf(-s_ab[1][t]));
            float Nv = Npop[n];
            float Iv = I0[n], Rv = R0[n];
            float SoN = (Nv - Iv - Rv) / Nv;
            for (int st = 0; st < 15; st++) {
                float dI = alpha * Iv * SoN - beta * Iv;
                float dR = beta * Iv;
                phyI[(size_t)n * 15 + st] = dI;
                phyR[(size_t)n * 15 + st] = dR;
                Iv += dI; Rv += dR;
            }
        }
    }
}

extern "C" void kernel_launch(void* const* d_in, const int* in_sizes, int n_in,
                              void* d_out, int out_size, void* d_ws, size_t ws_size,
                              hipStream_t stream) {
    const float* dynamic = (const float*)d_in[0];
    const int*   ei      = (const int*)d_in[1];
    const float* cI      = (const float*)d_in[2];
    const float* cR      = (const float*)d_in[3];
    const float* Npop    = (const float*)d_in[4];
    const float* I0      = (const float*)d_in[5];
    const float* R0      = (const float*)d_in[6];
    const float* W1      = (const float*)d_in[9];
    const float* a_src1  = (const float*)d_in[10];
    const float* a_dst1  = (const float*)d_in[11];
    const float* b1      = (const float*)d_in[12];
    const float* W2      = (const float*)d_in[13];
    const float* a_src2  = (const float*)d_in[14];
    const float* a_dst2  = (const float*)d_in[15];
    const float* b2      = (const float*)d_in[16];
    const float* W_ih    = (const float*)d_in[17];
    const float* b_ih    = (const float*)d_in[19];
    const float* b_hh    = (const float*)d_in[20];
    const float* W_I     = (const float*)d_in[21];
    const float* b_I     = (const float*)d_in[22];
    const float* W_R     = (const float*)d_in[23];
    const float* b_R     = (const float*)d_in[24];
    const float* W_sir   = (const float*)d_in[25];
    const float* b_sir   = (const float*)d_in[26];
    float* out = (float*)d_out;
    float* out_predI = out;
    float* out_predR = out + 300000;
    float* out_phyI  = out + 600000;
    float* out_phyR  = out + 900000;
    float* out_h     = out + 1200000;   // [20000][128] f32

    // ---- workspace layout ----
    int* wsi = (int*)d_ws;
    int* offs    = wsi;              // 20001 (pad 20096)
    int* csr_src = wsi + 20096;      // 660000 (pad 660096)
    ushort* cnt  = (ushort*)(wsi + 680192);  // 65536 ushorts (32768 ints)
    int* sbase   = wsi + 712960;     // 65536
    float* fp = (float*)(wsi + 778496);
    float* w1f = fp; fp += 1152;     // 128*8
    float* w2f = fp; fp += 512;      // 256*2
    float* wc  = fp; fp += 64;
    float* wb  = fp; fp += 64;
    float* al1 = fp; fp += 80128;    // 20000*4
    float* ar1 = fp; fp += 80128;
    float* al2 = fp; fp += 20096;
    float* ar2 = fp; fp += 20096;
    // fragment-packed bf16 weights (ushort)
    ushort* wub  = (ushort*)fp; fp += 118784;  // 237568 ushorts
    ushort* w1fh = wub;            // 32768
    ushort* w1fl = wub + 32768;
    ushort* w2fh = wub + 65536;    // 32768
    ushort* w2fl = wub + 98304;
    ushort* w3fh = wub + 131072;   // 49152
    ushort* w3fl = wub + 180224;
    ushort* wtfh = wub + 229376;   // 4096
    ushort* wtfl = wub + 233472;
    ushort* dyn_bf = (ushort*)fp; fp += 1280000;   // 20000*128 bf16
    ushort* x1u = (ushort*)fp; fp += 2560000;      // [20000][256] bf16
    ushort* x2u = x1u;                             // [20000][128] bf16 (x1 dead)
    float* R  = fp; fp += 7680000;                 // ebuf / agg_bf / xl2_bf / gi_bf
    int* ebuf = (int*)R;                           // [640000] packed src|dst<<15
    ushort* agg_bf = (ushort*)R;                   // [20000][512] bf16
    ushort* xl2_bf = (ushort*)R;                   // [20000][128] bf16 (after agg dead)
    ushort* gi_bf  = (ushort*)R;                   // [20000][384] bf16 (after xl2 dead)

    // CSR build + weight prep (packs parallelized over 58 blocks)
    csrA_kernel<<<NSL + 3 + 58, 256, 0, stream>>>(ei, cnt, W1, a_src1, a_dst1, w1f,
                                                  W2, a_src2, a_dst2, w2f, W_ih,
                                                  W_I, b_I, W_R, b_R, W_sir, b_sir,
                                                  w1fh, w1fl, w2fh, w2fl, w3fh, w3fl,
                                                  wtfh, wtfl, wc, wb);
    csrB_kernel<<<1, 1024, 0, stream>>>(cnt, sbase);
    csrC_kernel<<<NSL + 5000, 256, 0, stream>>>(ei, sbase, ebuf, dynamic, w1f,
                                                dyn_bf, al1, ar1);
    csrD_kernel<<<NB, 256, 0, stream>>>(ebuf, sbase, offs, csr_src);

    // GAT layer 1
    gat_gather_w<4, false><<<5000, 256, 0, stream>>>(dyn_bf, al1, ar1, offs, csr_src, nullptr, agg_bf);
    gemm_fr<1, true, false, 1><<<dim3(313, 1, 4), 256, 0, stream>>>(
        agg_bf, w1fh, w1fl, b1, x1u, NN, 128, 512, 256, 128, 64, 64,
        nullptr, nullptr, nullptr);

    // GAT layer 2 (al2/ar2 fused into GEMM via w2f fold, y==0 blocks only)
    gemm_fr<0, true, true, 1><<<dim3(313, 2, 1), 256, 0, stream>>>(
        x1u, w2fh, w2fl, nullptr, xl2_bf, NN, 256, 256, 128, 0, 0, 0,
        w2f, al2, ar2);
    gat_gather_w<1, true><<<5000, 256, 0, stream>>>(xl2_bf, al2, ar2, offs, csr_src, b2, x2u);

    // gi = x2 @ W_ih^T (N=384 via z gates, NF=2 -> BN=128 per block), bf16 output
    gemm_fr<0, true, false, 2><<<dim3(313, 1, 3), 256, 0, stream>>>(
        x2u, w3fh, w3fl, nullptr, gi_bf, NN, 128, 128, 384, 0, 128, 128,
        nullptr, nullptr, nullptr);

    // GRU + heads + SIR
    tail_kernel<<<313, 256, 0, stream>>>(gi_bf, b_ih, b_hh, wtfh, wtfl, wc, wb,
                                         cI, cR, Npop, I0, R0, out_h,
                                         out_predI, out_predR, out_phyI, out_phyR);
}